// Round 9
// baseline (559.346 us; speedup 1.0000x reference)
//
#include <hip/hip_runtime.h>
#include <hip/hip_bf16.h>
#include <stdint.h>

typedef float f32x4 __attribute__((ext_vector_type(4)));
typedef int i32x4 __attribute__((ext_vector_type(4)));

#define MROWS 8192
#define DD 1024
#define DN 4096
#define CAP 160   // compact-row capacity: 64 + tie headroom

__device__ __forceinline__ void load_lds16(const void* g, void* l) {
  __builtin_amdgcn_global_load_lds((const __attribute__((address_space(1))) void*)g,
                                   (__attribute__((address_space(3))) void*)l, 16, 0, 0);
}

__device__ __forceinline__ unsigned f32_to_bf16_rne(float f) {
  unsigned u = __float_as_uint(f);
  return (u + 0x7fffu + ((u >> 16) & 1u)) >> 16;
}

// ============================================================================
// 256x256 8-phase INT8 GEMM (round-7 verified schedule; pipelined frag reads,
// vmcnt(6) odd phases). K bytes, K-tile=128B, NT=K>>7. h1 = relu(deq)->bf16.
// ============================================================================
__global__ void __launch_bounds__(512, 1)
gemm_i8_8ph(const uint8_t* __restrict__ A, const uint8_t* __restrict__ B,
            __hip_bfloat16* __restrict__ Cb, int M, int N, int K,
            const float* __restrict__ sA, const float* __restrict__ sB)
{
  extern __shared__ __align__(16) char smem[];
  const int tid  = threadIdx.x;
  const int lane = tid & 63;
  const int wave = tid >> 6;
  const int wm = wave >> 2;
  const int wn = wave & 3;

  const int nwg = gridDim.x;
  const int bid = ((int)blockIdx.x % 8) * (nwg >> 3) + ((int)blockIdx.x >> 3);

  const int nbn = N >> 8;
  const int bm = (bid / nbn) << 8;
  const int bn = (bid % nbn) << 8;

  const int NT = K >> 7;

  i32x4 acc[8][4];
  const i32x4 izero = {0, 0, 0, 0};
#pragma unroll
  for (int i = 0; i < 8; ++i)
#pragma unroll
    for (int j = 0; j < 4; ++j)
      acc[i][j] = izero;

  const int csb = (((tid & 3) ^ ((tid >> 3) & 3)) << 4);
  const uint8_t* Ag = A + (size_t)(bm + (tid >> 2)) * K + csb;
  const uint8_t* Bg = B + (size_t)(bn + (tid >> 2)) * K + csb;

  const int rl = lane & 15;
  const int kc = lane >> 4;
  const int chunk_off = ((kc ^ ((rl >> 1) & 3)) << 4);
  const int aoff = ((wm << 7) + rl) * 64 + chunk_off;
  const int boff = ((wn << 6) + rl) * 64 + chunk_off;

#define STAGE_A8(S, KH) do { \
    const int kt_ = (((S) & (NT - 1)) << 7) + ((KH) << 6); \
    char* dst_ = smem + (((((S) & 1) << 1) | (KH)) << 14) + (tid << 4); \
    load_lds16(Ag + kt_, dst_); \
    load_lds16(Ag + (size_t)128 * K + kt_, dst_ + 8192); \
  } while (0)

#define STAGE_B8(S, KH) do { \
    const int kt_ = (((S) & (NT - 1)) << 7) + ((KH) << 6); \
    char* dst_ = smem + 65536 + (((((S) & 1) << 1) | (KH)) << 14) + (tid << 4); \
    load_lds16(Bg + kt_, dst_); \
    load_lds16(Bg + (size_t)128 * K + kt_, dst_ + 8192); \
  } while (0)

  i32x4 afS[2][4];
  i32x4 b0, b1, b2, b3;

#define MFMA_ROW8(MI, AF) \
    acc[MI][0] = __builtin_amdgcn_mfma_i32_16x16x64_i8(AF, b0, acc[MI][0], 0, 0, 0); \
    acc[MI][1] = __builtin_amdgcn_mfma_i32_16x16x64_i8(AF, b1, acc[MI][1], 0, 0, 0); \
    acc[MI][2] = __builtin_amdgcn_mfma_i32_16x16x64_i8(AF, b2, acc[MI][2], 0, 0, 0); \
    acc[MI][3] = __builtin_amdgcn_mfma_i32_16x16x64_i8(AF, b3, acc[MI][3], 0, 0, 0);

#define PH8(PN, KHN, MHN, ASETN, ACUR, MHC, DOBP, BP, BKH, STG, VM) do { \
    { const char* ab_ = smem + ((((PN) << 1) | (KHN)) << 14) + aoff + (MHN) * 4096; \
      afS[ASETN][0] = *(const i32x4*)(ab_); \
      afS[ASETN][1] = *(const i32x4*)(ab_ + 1024); \
      afS[ASETN][2] = *(const i32x4*)(ab_ + 2048); \
      afS[ASETN][3] = *(const i32x4*)(ab_ + 3072); } \
    STG; \
    if (VM) { asm volatile("s_waitcnt vmcnt(6)" ::: "memory"); } \
    asm volatile("s_barrier" ::: "memory"); \
    __builtin_amdgcn_sched_barrier(0); \
    __builtin_amdgcn_s_setprio(1); \
    MFMA_ROW8((MHC) * 4 + 0, afS[ACUR][0]) \
    MFMA_ROW8((MHC) * 4 + 1, afS[ACUR][1]) \
    MFMA_ROW8((MHC) * 4 + 2, afS[ACUR][2]) \
    MFMA_ROW8((MHC) * 4 + 3, afS[ACUR][3]) \
    __builtin_amdgcn_s_setprio(0); \
    if (DOBP) { \
      const char* bb_ = smem + 65536 + ((((BP) << 1) | (BKH)) << 14) + boff; \
      b0 = *(const i32x4*)(bb_); b1 = *(const i32x4*)(bb_ + 1024); \
      b2 = *(const i32x4*)(bb_ + 2048); b3 = *(const i32x4*)(bb_ + 3072); } \
    asm volatile("s_barrier" ::: "memory"); \
  } while (0)

  STAGE_A8(0, 0); STAGE_B8(0, 0);
  STAGE_A8(0, 1); STAGE_B8(0, 1);
  STAGE_A8(1, 0); STAGE_B8(1, 0);
  asm volatile("s_waitcnt vmcnt(4)" ::: "memory");
  asm volatile("s_barrier" ::: "memory");
  {
    const char* ab_ = smem + aoff;
    afS[1][0] = *(const i32x4*)(ab_);
    afS[1][1] = *(const i32x4*)(ab_ + 1024);
    afS[1][2] = *(const i32x4*)(ab_ + 2048);
    afS[1][3] = *(const i32x4*)(ab_ + 3072);
    const char* bb_ = smem + 65536 + boff;
    b0 = *(const i32x4*)(bb_); b1 = *(const i32x4*)(bb_ + 1024);
    b2 = *(const i32x4*)(bb_ + 2048); b3 = *(const i32x4*)(bb_ + 3072);
  }

#pragma unroll 1
  for (int t = 0; t < NT; t += 2) {
    PH8(0, 0, 1, 0, 1, 0, 0, 0, 0, STAGE_A8(t + 1, 1), 1);
    PH8(0, 1, 0, 1, 0, 1, 1, 0, 1, STAGE_B8(t + 1, 1), 0);
    PH8(0, 1, 1, 0, 1, 0, 0, 0, 0, STAGE_A8(t + 2, 0), 1);
    PH8(1, 0, 0, 1, 0, 1, 1, 1, 0, STAGE_B8(t + 2, 0), 0);
    PH8(1, 0, 1, 0, 1, 0, 0, 0, 0, STAGE_A8(t + 2, 1), 1);
    PH8(1, 1, 0, 1, 0, 1, 1, 1, 1, STAGE_B8(t + 2, 1), 0);
    PH8(1, 1, 1, 0, 1, 0, 0, 0, 0, STAGE_A8(t + 3, 0), 1);
    PH8(0, 0, 0, 1, 0, 1, 1, 0, 0, STAGE_B8(t + 3, 0), 0);
  }

  const int r0 = bm + (wm << 7) + (kc << 2);
  const int c0 = bn + (wn << 6) + rl;
#pragma unroll
  for (int mi = 0; mi < 8; ++mi) {
#pragma unroll
    for (int nf = 0; nf < 4; ++nf) {
#pragma unroll
      for (int q = 0; q < 4; ++q) {
        const int r = r0 + (mi << 4) + q;
        const int c = c0 + (nf << 4);
        float v = (float)acc[mi][nf][q] * sA[r] * sB[c];
        Cb[(size_t)r * N + c] = __float2bfloat16(fmaxf(v, 0.f));
      }
    }
  }

#undef STAGE_A8
#undef STAGE_B8
#undef MFMA_ROW8
#undef PH8
}

// ============================================================================
// Dense i8 128x128 2-barrier GEMM — gate logits: glin = (xq@wgq^T)*sx*swg
// -> bf16 (no bias/sigmoid here; final_gather applies them).
// ============================================================================
__global__ void __launch_bounds__(256)
gemm_gate_i8(const uint8_t* __restrict__ A, const uint8_t* __restrict__ B,
             __hip_bfloat16* __restrict__ Cb, int M, int N, int K,
             const float* __restrict__ sA, const float* __restrict__ sB)
{
  __shared__ __align__(16) char smem[32768];
  const int tid  = threadIdx.x;
  const int lane = tid & 63;
  const int wave = tid >> 6;

  const int nbn = N >> 7;
  const int bm = ((int)blockIdx.x / nbn) << 7;
  const int bn = ((int)blockIdx.x % nbn) << 7;

  const int wm = (wave >> 1) << 6;
  const int wn = (wave & 1) << 6;

  i32x4 acc[4][4];
  const i32x4 izero = {0, 0, 0, 0};
#pragma unroll
  for (int i = 0; i < 4; ++i)
#pragma unroll
    for (int j = 0; j < 4; ++j) acc[i][j] = izero;

  const int srow = tid >> 3;
  const int schk = (tid & 7) ^ (srow & 7);
  const uint8_t* Ag = A + (size_t)(bm + srow) * K + (schk << 4);
  const uint8_t* Bg = B + (size_t)(bn + srow) * K + (schk << 4);
  char* ldsA = smem + (wave << 10);
  char* ldsB = smem + 16384 + (wave << 10);

  const int aoff0 = (wm + (lane & 15)) << 7;
  const int boff0 = 16384 + ((wn + (lane & 15)) << 7);
  const int kc = lane >> 4;
  const int sw = lane & 7;

  for (int k0 = 0; k0 < K; k0 += 128) {
#pragma unroll
    for (int i = 0; i < 4; ++i)
      load_lds16(Ag + (size_t)(i << 5) * K + k0, ldsA + (i << 12));
#pragma unroll
    for (int i = 0; i < 4; ++i)
      load_lds16(Bg + (size_t)(i << 5) * K + k0, ldsB + (i << 12));
    __syncthreads();
#pragma unroll
    for (int ks = 0; ks < 2; ++ks) {
      const int cb = ((kc + (ks << 2)) ^ sw) << 4;
      i32x4 af[4], bfr[4];
#pragma unroll
      for (int i = 0; i < 4; ++i)
        af[i] = *reinterpret_cast<const i32x4*>(smem + aoff0 + (i << 11) + cb);
#pragma unroll
      for (int j = 0; j < 4; ++j)
        bfr[j] = *reinterpret_cast<const i32x4*>(smem + boff0 + (j << 11) + cb);
#pragma unroll
      for (int i = 0; i < 4; ++i)
#pragma unroll
        for (int j = 0; j < 4; ++j)
          acc[i][j] = __builtin_amdgcn_mfma_i32_16x16x64_i8(af[i], bfr[j], acc[i][j], 0, 0, 0);
    }
    __syncthreads();
  }

  const int r0 = bm + wm + ((lane >> 4) << 2);
  const int c0 = bn + wn + (lane & 15);
#pragma unroll
  for (int i = 0; i < 4; ++i)
#pragma unroll
    for (int j = 0; j < 4; ++j)
#pragma unroll
      for (int q = 0; q < 4; ++q) {
        const int r = r0 + (i << 4) + q;
        const int c = c0 + (j << 4);
        Cb[(size_t)r * N + c] =
            __float2bfloat16((float)acc[i][j][q] * sA[r] * sB[c]);
      }
}

// ============================================================================
// kwta -> COMPACT output. Wave per row; exact binary-search threshold on u16
// bf16 keys; writes (idx u16, val f32 normalized) pairs for kept NONZERO
// elements + count (clamped to CAP; zeros contribute nothing downstream).
// ============================================================================
__global__ void __launch_bounds__(256)
kwta_compact(const __hip_bfloat16* __restrict__ H,
             unsigned short* __restrict__ sp_idx, float* __restrict__ sp_val,
             unsigned* __restrict__ sp_cnt, const int* __restrict__ kptr)
{
  const int tid  = threadIdx.x;
  const int lane = tid & 63;
  const int w    = tid >> 6;
  const int row  = ((int)blockIdx.x << 2) + w;

  const uint4* h8 = (const uint4*)(H + (size_t)row * 4096);
  uint4 d[8];
#pragma unroll
  for (int i = 0; i < 8; ++i) d[i] = h8[(i << 6) + lane];

  const unsigned k = (unsigned)(*kptr);

  unsigned lo = 0, hi = 65536;
#pragma unroll 1
  for (int it = 0; it < 16; ++it) {
    const unsigned mid = (lo + hi) >> 1;
    unsigned c = 0;
#pragma unroll
    for (int i = 0; i < 8; ++i) {
      const unsigned* p = (const unsigned*)&d[i];
#pragma unroll
      for (int c4 = 0; c4 < 4; ++c4) {
        c += ((p[c4] & 0xffffu) >= mid) ? 1u : 0u;
        c += ((p[c4] >> 16) >= mid) ? 1u : 0u;
      }
    }
#pragma unroll
    for (int off = 32; off > 0; off >>= 1) c += __shfl_xor(c, off);
    if (c >= k) lo = mid; else hi = mid;
  }
  const unsigned T = lo;

  float ss = 0.f;
  unsigned kc = 0;
#pragma unroll
  for (int i = 0; i < 8; ++i) {
    const unsigned* p = (const unsigned*)&d[i];
#pragma unroll
    for (int c4 = 0; c4 < 4; ++c4) {
#pragma unroll
      for (int hh = 0; hh < 2; ++hh) {
        const unsigned key = hh ? (p[c4] >> 16) : (p[c4] & 0xffffu);
        if (key >= T && key > 0) {
          const float v = __uint_as_float(key << 16);
          ss = fmaf(v, v, ss);
          ++kc;
        }
      }
    }
  }
#pragma unroll
  for (int off = 32; off > 0; off >>= 1) ss += __shfl_xor(ss, off);
  const float inv = 1.f / fmaxf(sqrtf(ss), 1e-10f);

  // wave exclusive scan of per-lane kept counts
  unsigned inc = kc;
#pragma unroll
  for (int off = 1; off < 64; off <<= 1) {
    const unsigned n = __shfl_up(inc, off);
    if (lane >= off) inc += n;
  }
  unsigned pos = inc - kc;
  const unsigned total = __shfl(inc, 63);

  const size_t base = (size_t)row * CAP;
#pragma unroll
  for (int i = 0; i < 8; ++i) {
    const unsigned* p = (const unsigned*)&d[i];
#pragma unroll
    for (int c4 = 0; c4 < 4; ++c4) {
#pragma unroll
      for (int hh = 0; hh < 2; ++hh) {
        const unsigned key = hh ? (p[c4] >> 16) : (p[c4] & 0xffffu);
        if (key >= T && key > 0) {
          if (pos < CAP) {
            sp_idx[base + pos] = (unsigned short)((((i << 6) + lane) << 3) + c4 * 2 + hh);
            sp_val[base + pos] = __uint_as_float(key << 16) * inv;
          }
          ++pos;
        }
      }
    }
  }
  if (lane == 0) sp_cnt[row] = total < CAP ? total : CAP;
}

// ============================================================================
// CA3 sparse gather + fused kwta. Block = one row (256 thr, 16 outputs each,
// c = tid*16+e). h2[c] = swc[c] * (Sum_i v_i * wct[j_i][c]); wct is excess-128
// i8 (byte = q+128), corrected by 128*Sum(v). relu -> bf16-round -> block kwta
// (binary search + compaction) -> succ compact + atomicAdd(vsum, rowsum).
// ============================================================================
__global__ void __launch_bounds__(256)
ca3_gather(const unsigned short* __restrict__ sp_idx, const float* __restrict__ sp_val,
           const unsigned* __restrict__ sp_cnt,
           const uint8_t* __restrict__ wct, const float* __restrict__ swc,
           unsigned short* __restrict__ succ_idx, float* __restrict__ succ_val,
           unsigned* __restrict__ succ_cnt,
           float* __restrict__ vsum, const int* __restrict__ kptr)
{
  __shared__ float redf[4];
  __shared__ unsigned redu[8];

  const int row  = blockIdx.x;
  const int tid  = threadIdx.x;
  const int lane = tid & 63;
  const int w    = tid >> 6;
  const int cb   = tid << 4;   // first output col of this thread

  const int cnt = (int)sp_cnt[row];
  const unsigned short* ji = sp_idx + (size_t)row * CAP;
  const float* vi = sp_val + (size_t)row * CAP;

  float acc[16];
#pragma unroll
  for (int e = 0; e < 16; ++e) acc[e] = 0.f;
  float vsumc = 0.f;

  uint4 wcur = {0, 0, 0, 0};
  float v0 = 0.f;
  if (cnt > 0) {
    const int j0 = ji[0];
    v0 = vi[0];
    wcur = *(const uint4*)(wct + (size_t)j0 * 4096 + cb);
  }
#pragma unroll 1
  for (int i = 0; i < cnt; ++i) {
    uint4 wn = {0, 0, 0, 0};
    float vn = 0.f;
    if (i + 1 < cnt) {
      const int jn = ji[i + 1];
      vn = vi[i + 1];
      wn = *(const uint4*)(wct + (size_t)jn * 4096 + cb);
    }
    const float v = v0;
    vsumc += v;
#define UNP(word, b_) \
    acc[b_ + 0] = fmaf(v, (float)((word) & 0xffu), acc[b_ + 0]); \
    acc[b_ + 1] = fmaf(v, (float)(((word) >> 8) & 0xffu), acc[b_ + 1]); \
    acc[b_ + 2] = fmaf(v, (float)(((word) >> 16) & 0xffu), acc[b_ + 2]); \
    acc[b_ + 3] = fmaf(v, (float)((word) >> 24), acc[b_ + 3]);
    UNP(wcur.x, 0) UNP(wcur.y, 4) UNP(wcur.z, 8) UNP(wcur.w, 12)
#undef UNP
    wcur = wn; v0 = vn;
  }

  const float corr = 128.f * vsumc;
  float vals[16];
  unsigned keys[16];
  float rs = 0.f;
#pragma unroll
  for (int e = 0; e < 16; ++e) {
    const float h = fmaxf((acc[e] - corr) * swc[cb + e], 0.f);
    const unsigned kk = f32_to_bf16_rne(h);
    keys[e] = kk;
    vals[e] = __uint_as_float(kk << 16);
    rs += vals[e];
  }

  // row sum -> vsum
#pragma unroll
  for (int off = 32; off > 0; off >>= 1) rs += __shfl_xor(rs, off);
  if (lane == 0) redf[w] = rs;
  __syncthreads();
  if (tid == 0) atomicAdd(vsum, redf[0] + redf[1] + redf[2] + redf[3]);

  // block binary search for threshold
  const unsigned k = (unsigned)(*kptr);
  unsigned lo = 0, hi = 65536;
#pragma unroll 1
  for (int it = 0; it < 16; ++it) {
    const unsigned mid = (lo + hi) >> 1;
    unsigned c = 0;
#pragma unroll
    for (int e = 0; e < 16; ++e) c += (keys[e] >= mid) ? 1u : 0u;
#pragma unroll
    for (int off = 32; off > 0; off >>= 1) c += __shfl_xor(c, off);
    if (lane == 0) redu[w] = c;
    __syncthreads();
    const unsigned tot = redu[0] + redu[1] + redu[2] + redu[3];
    if (tot >= k) lo = mid; else hi = mid;
    __syncthreads();
  }
  const unsigned T = lo;

  // norm over kept
  float ss = 0.f;
  unsigned kc = 0;
#pragma unroll
  for (int e = 0; e < 16; ++e) {
    if (keys[e] >= T && keys[e] > 0) {
      ss = fmaf(vals[e], vals[e], ss);
      ++kc;
    }
  }
#pragma unroll
  for (int off = 32; off > 0; off >>= 1) ss += __shfl_xor(ss, off);
  if (lane == 0) redf[w] = ss;
  __syncthreads();
  const float inv = 1.f / fmaxf(sqrtf(redf[0] + redf[1] + redf[2] + redf[3]), 1e-10f);

  // block exclusive scan of kept counts
  unsigned inc = kc;
#pragma unroll
  for (int off = 1; off < 64; off <<= 1) {
    const unsigned n = __shfl_up(inc, off);
    if (lane >= off) inc += n;
  }
  if (lane == 63) redu[4 + w] = inc;
  __syncthreads();
  unsigned wbase = 0;
#pragma unroll
  for (int ww = 0; ww < 4; ++ww)
    if (ww < w) wbase += redu[4 + ww];
  unsigned pos = wbase + inc - kc;
  const unsigned total = redu[4] + redu[5] + redu[6] + redu[7];

  const size_t base = (size_t)row * CAP;
#pragma unroll
  for (int e = 0; e < 16; ++e) {
    if (keys[e] >= T && keys[e] > 0) {
      if (pos < CAP) {
        succ_idx[base + pos] = (unsigned short)(cb + e);
        succ_val[base + pos] = vals[e] * inv;
      }
      ++pos;
    }
  }
  if (tid == 0) succ_cnt[row] = total < CAP ? total : CAP;
}

// ============================================================================
// Final: pred gather (sparse successor @ W_up^T via excess-128 i8 wut) fused
// with gate sigmoid + residual: out = x + sigmoid(glin + bg) * pred.
// Block = row; 4 outputs/thread (c = tid*4+e). valid-select sp vs succ.
// ============================================================================
__global__ void __launch_bounds__(256)
final_gather(const unsigned short* __restrict__ sp_idx, const float* __restrict__ sp_val,
             const unsigned* __restrict__ sp_cnt,
             const unsigned short* __restrict__ succ_idx, const float* __restrict__ succ_val,
             const unsigned* __restrict__ succ_cnt,
             const float* __restrict__ vsum,
             const uint8_t* __restrict__ wut, const float* __restrict__ swu,
             const __hip_bfloat16* __restrict__ glin, const float* __restrict__ bg,
             const float* __restrict__ x, float* __restrict__ out)
{
  const int row = blockIdx.x;
  const int tid = threadIdx.x;
  const int cb  = tid << 2;

  const bool valid = (*vsum >= 1e-10f);
  const unsigned short* ji = (valid ? succ_idx : sp_idx) + (size_t)row * CAP;
  const float* vi = (valid ? succ_val : sp_val) + (size_t)row * CAP;
  const int cnt = (int)((valid ? succ_cnt : sp_cnt)[row]);

  float acc[4] = {0.f, 0.f, 0.f, 0.f};
  float vs = 0.f;

  unsigned wcur = 0;
  float v0 = 0.f;
  if (cnt > 0) {
    const int j0 = ji[0];
    v0 = vi[0];
    wcur = *(const unsigned*)(wut + (size_t)j0 * 1024 + cb);
  }
#pragma unroll 1
  for (int i = 0; i < cnt; ++i) {
    unsigned wn = 0;
    float vn = 0.f;
    if (i + 1 < cnt) {
      const int jn = ji[i + 1];
      vn = vi[i + 1];
      wn = *(const unsigned*)(wut + (size_t)jn * 1024 + cb);
    }
    const float v = v0;
    vs += v;
    acc[0] = fmaf(v, (float)(wcur & 0xffu), acc[0]);
    acc[1] = fmaf(v, (float)((wcur >> 8) & 0xffu), acc[1]);
    acc[2] = fmaf(v, (float)((wcur >> 16) & 0xffu), acc[2]);
    acc[3] = fmaf(v, (float)(wcur >> 24), acc[3]);
    wcur = wn; v0 = vn;
  }

  const float corr = 128.f * vs;
  const size_t rbase = (size_t)row * 1024;
#pragma unroll
  for (int e = 0; e < 4; ++e) {
    const int c = cb + e;
    const float pred = (acc[e] - corr) * swu[c];
    const float gl = __bfloat162float(glin[rbase + c]) + bg[c];
    const float g = 1.f / (1.f + __expf(-gl));
    out[rbase + c] = x[rbase + c] + g * pred;
  }
}

// ============================================================================
// quantization (round-8 verified): per-row absmax i8.
// ============================================================================
__global__ void __launch_bounds__(256)
quant1024(const float* __restrict__ X, const float* __restrict__ Wd,
          const float* __restrict__ Wg,
          uint8_t* __restrict__ xq, uint8_t* __restrict__ wdq,
          uint8_t* __restrict__ wgq,
          float* __restrict__ sx, float* __restrict__ swd,
          float* __restrict__ swg)
{
  const int wgl = ((int)blockIdx.x << 2) + (threadIdx.x >> 6);
  const int lane = threadIdx.x & 63;

  const float* W; uint8_t* q; float* s; int row;
  if      (wgl < 8192)  { W = X;  q = xq;  s = sx;  row = wgl; }
  else if (wgl < 12288) { W = Wd; q = wdq; s = swd; row = wgl - 8192; }
  else                  { W = Wg; q = wgq; s = swg; row = wgl - 12288; }

  const float4* src = (const float4*)(W + (size_t)row * 1024);
  float4 v[4];
  float am = 0.f;
#pragma unroll
  for (int i = 0; i < 4; ++i) {
    v[i] = src[(i << 6) + lane];
    am = fmaxf(am, fmaxf(fmaxf(fabsf(v[i].x), fabsf(v[i].y)),
                         fmaxf(fabsf(v[i].z), fabsf(v[i].w))));
  }
#pragma unroll
  for (int off = 32; off > 0; off >>= 1) am = fmaxf(am, __shfl_xor(am, off));

  const float rinv = (am > 0.f) ? 127.f / am : 0.f;
  uint4 o;
  unsigned* ob = (unsigned*)&o;
#pragma unroll
  for (int i = 0; i < 4; ++i) {
    const unsigned b0 = (unsigned)__float2int_rn(v[i].x * rinv) & 0xffu;
    const unsigned b1 = (unsigned)__float2int_rn(v[i].y * rinv) & 0xffu;
    const unsigned b2 = (unsigned)__float2int_rn(v[i].z * rinv) & 0xffu;
    const unsigned b3 = (unsigned)__float2int_rn(v[i].w * rinv) & 0xffu;
    ob[i] = b0 | (b1 << 8) | (b2 << 16) | (b3 << 24);
  }
  ((uint4*)(q + (size_t)row * 1024))[lane] = o;
  if (lane == 0) s[row] = am * (1.f / 127.f);
}

__global__ void __launch_bounds__(256)
quant4096(const float* __restrict__ Wc, const float* __restrict__ Wu,
          uint8_t* __restrict__ qc, uint8_t* __restrict__ qu,
          float* __restrict__ sc, float* __restrict__ su)
{
  const int wgl = ((int)blockIdx.x << 2) + (threadIdx.x >> 6);
  const int lane = threadIdx.x & 63;

  const float* W; uint8_t* q; float* s; int row;
  if (wgl < 4096) { W = Wc; q = qc; s = sc; row = wgl; }
  else            { W = Wu; q = qu; s = su; row = wgl - 4096; }

  const float4* src = (const float4*)(W + (size_t)row * 4096);
  float4 v[16];
  float am = 0.f;
#pragma unroll
  for (int i = 0; i < 16; ++i) {
    v[i] = src[(i << 6) + lane];
    am = fmaxf(am, fmaxf(fmaxf(fabsf(v[i].x), fabsf(v[i].y)),
                         fmaxf(fabsf(v[i].z), fabsf(v[i].w))));
  }
#pragma unroll
  for (int off = 32; off > 0; off >>= 1) am = fmaxf(am, __shfl_xor(am, off));

  const float rinv = (am > 0.f) ? 127.f / am : 0.f;
  unsigned* qo = (unsigned*)(q + (size_t)row * 4096);
#pragma unroll
  for (int i = 0; i < 16; ++i) {
    const unsigned b0 = (unsigned)__float2int_rn(v[i].x * rinv) & 0xffu;
    const unsigned b1 = (unsigned)__float2int_rn(v[i].y * rinv) & 0xffu;
    const unsigned b2 = (unsigned)__float2int_rn(v[i].z * rinv) & 0xffu;
    const unsigned b3 = (unsigned)__float2int_rn(v[i].w * rinv) & 0xffu;
    qo[(i << 6) + lane] = b0 | (b1 << 8) | (b2 << 16) | (b3 << 24);
  }
  if (lane == 0) s[row] = am * (1.f / 127.f);
}

// ============================================================================
// i8 transpose (64x64 byte tiles) with two's-complement -> excess-128 (^0x80).
// blocks 0..4095: wcq[4096][4096] -> wct[j][c]. 4096..5119: wuq[1024][4096]
// -> wut[4096][1024].
// ============================================================================
__global__ void __launch_bounds__(256)
transpose_i8(const uint8_t* __restrict__ wcq, uint8_t* __restrict__ wct,
             const uint8_t* __restrict__ wuq, uint8_t* __restrict__ wut)
{
  __shared__ char tile[64][68];
  int b = blockIdx.x;
  const uint8_t* src; uint8_t* dst; int c0, j0, Kd;
  if (b < 4096) { src = wcq; dst = wct; c0 = (b >> 6) << 6; j0 = (b & 63) << 6; Kd = 4096; }
  else { b -= 4096; src = wuq; dst = wut; c0 = (b >> 6) << 6; j0 = (b & 63) << 6; Kd = 1024; }

  const int t = threadIdx.x;
  const int r = t >> 2;
  const int ch = t & 3;

  const uint4 v = *(const uint4*)(src + (size_t)(c0 + r) * 4096 + j0 + (ch << 4));
  *(unsigned*)&tile[r][(ch << 4) + 0]  = v.x;
  *(unsigned*)&tile[r][(ch << 4) + 4]  = v.y;
  *(unsigned*)&tile[r][(ch << 4) + 8]  = v.z;
  *(unsigned*)&tile[r][(ch << 4) + 12] = v.w;
  __syncthreads();

  uint4 o;
  unsigned* ow = (unsigned*)&o;
#pragma unroll
  for (int qw = 0; qw < 4; ++qw) {
    const int ccb = (ch << 4) + (qw << 2);
    const unsigned b0 = (unsigned)(unsigned char)tile[ccb + 0][r];
    const unsigned b1 = (unsigned)(unsigned char)tile[ccb + 1][r];
    const unsigned b2 = (unsigned)(unsigned char)tile[ccb + 2][r];
    const unsigned b3 = (unsigned)(unsigned char)tile[ccb + 3][r];
    ow[qw] = (b0 | (b1 << 8) | (b2 << 16) | (b3 << 24)) ^ 0x80808080u;
  }
  *(uint4*)(dst + (size_t)(j0 + r) * Kd + c0 + (ch << 4)) = o;
}

__global__ void diag_kernel(float* out, float mb)
{
  if (threadIdx.x == 0 && blockIdx.x == 0) out[0] = -mb;
}

extern "C" void kernel_launch(void* const* d_in, const int* in_sizes, int n_in,
                              void* d_out, int out_size, void* d_ws, size_t ws_size,
                              hipStream_t stream)
{
  const float* x     = (const float*)d_in[0]; // (8192,1024)
  const float* Wdown = (const float*)d_in[1]; // (4096,1024)
  const float* Wup   = (const float*)d_in[2]; // (1024,4096)
  const float* Wgate = (const float*)d_in[3]; // (1024,1024)
  const float* bgate = (const float*)d_in[4]; // (1024,)
  const float* Wca3  = (const float*)d_in[5]; // (4096,4096)
  const int*   kptr  = (const int*)d_in[6];

  const size_t OFF_XQ   = 0;          //  8 MB
  const size_t OFF_WDQ  = 8388608;    //  4 MB
  const size_t OFF_WGQ  = 12582912;   //  1 MB
  const size_t OFF_WCQ  = 13631488;   // 16 MB
  const size_t OFF_WUQ  = 30408704;   //  4 MB
  const size_t OFF_WCT  = 34603008;   // 16 MB (transposed, excess-128)
  const size_t OFF_WUT  = 51380224;   //  4 MB (transposed, excess-128)
  const size_t OFF_SX   = 55574528;   // 32 KB
  const size_t OFF_SWD  = 55607296;   // 16 KB
  const size_t OFF_SWG  = 55623680;   //  4 KB
  const size_t OFF_SWC  = 55627776;   // 16 KB
  const size_t OFF_SWU  = 55644160;   //  4 KB
  const size_t OFF_VSUM = 55648256;   //  4 KB pad
  const size_t OFF_SPI  = 55652352;   // 2.5 MB u16 idx
  const size_t OFF_SPV  = 58273792;   //  5 MB f32 val
  const size_t OFF_SPC  = 63516672;   // 32 KB cnt
  const size_t OFF_SUI  = 63549440;   // 2.5 MB
  const size_t OFF_SUV  = 66170880;   //  5 MB
  const size_t OFF_SUC  = 71413760;   // 32 KB
  const size_t OFF_GL   = 71446528;   // 16 MB bf16 gate logits
  const size_t OFF_H    = 88223744;   // 64 MB bf16 h1
  const size_t NEED     = 155332608;

  if (ws_size < NEED) {
    diag_kernel<<<1, 64, 0, stream>>>((float*)d_out, (float)(ws_size >> 20));
    return;
  }

  char* ws = (char*)d_ws;
  uint8_t*        xq   = (uint8_t*)(ws + OFF_XQ);
  uint8_t*        wdq  = (uint8_t*)(ws + OFF_WDQ);
  uint8_t*        wgq  = (uint8_t*)(ws + OFF_WGQ);
  uint8_t*        wcq  = (uint8_t*)(ws + OFF_WCQ);
  uint8_t*        wuq  = (uint8_t*)(ws + OFF_WUQ);
  uint8_t*        wct  = (uint8_t*)(ws + OFF_WCT);
  uint8_t*        wut  = (uint8_t*)(ws + OFF_WUT);
  float*          sx   = (float*)(ws + OFF_SX);
  float*          swd  = (float*)(ws + OFF_SWD);
  float*          swg  = (float*)(ws + OFF_SWG);
  float*          swc  = (float*)(ws + OFF_SWC);
  float*          swu  = (float*)(ws + OFF_SWU);
  float*          vsum = (float*)(ws + OFF_VSUM);
  unsigned short* spi  = (unsigned short*)(ws + OFF_SPI);
  float*          spv  = (float*)(ws + OFF_SPV);
  unsigned*       spc  = (unsigned*)(ws + OFF_SPC);
  unsigned short* sui  = (unsigned short*)(ws + OFF_SUI);
  float*          suv  = (float*)(ws + OFF_SUV);
  unsigned*       suc  = (unsigned*)(ws + OFF_SUC);
  __hip_bfloat16* gl   = (__hip_bfloat16*)(ws + OFF_GL);
  __hip_bfloat16* h    = (__hip_bfloat16*)(ws + OFF_H);

  hipMemsetAsync(vsum, 0, sizeof(float), stream);

  // quantize inputs/weights
  quant1024<<<3328, 256, 0, stream>>>(x, Wdown, Wgate, xq, wdq, wgq, sx, swd, swg);
  quant4096<<<1280, 256, 0, stream>>>(Wca3, Wup, wcq, wuq, swc, swu);
  // transpose W_ca3/W_up i8 -> excess-128 [j][c] layout
  transpose_i8<<<5120, 256, 0, stream>>>(wcq, wct, wuq, wut);

  // h1 = relu(deq(xq @ wdq^T)) -> bf16   [dense i8 8-phase 256^2, grid 512]
  gemm_i8_8ph<<<(MROWS >> 8) * (DN >> 8), 512, 131072, stream>>>(
      xq, wdq, h, MROWS, DN, DD, sx, swd);
  // sparse = kwta(h1)/norm -> compact (idx, val, cnt)
  kwta_compact<<<MROWS / 4, 256, 0, stream>>>(h, spi, spv, spc, kptr);
  // gate logits = deq(xq @ wgq^T) -> bf16   [dense i8 128^2, grid 512]
  gemm_gate_i8<<<(MROWS >> 7) * (DD >> 7), 256, 0, stream>>>(
      xq, wgq, gl, MROWS, DD, DD, sx, swg);
  // h2 = relu(sparse-gather @ wct) ; fused kwta -> succ compact ; vsum
  ca3_gather<<<MROWS, 256, 0, stream>>>(spi, spv, spc, wct, swc,
                                        sui, suv, suc, vsum, kptr);
  // out = x + sigmoid(gl + bg) * (successor-gather @ wut)
  final_gather<<<MROWS, 256, 0, stream>>>(spi, spv, spc, sui, suv, suc, vsum,
                                          wut, swu, gl, bgate, x, (float*)d_out);
}

// Round 10
// 457.501 us; speedup vs baseline: 1.2226x; 1.2226x over previous
//
#include <hip/hip_runtime.h>
#include <hip/hip_bf16.h>
#include <stdint.h>

typedef float f32x4 __attribute__((ext_vector_type(4)));
typedef int i32x4 __attribute__((ext_vector_type(4)));

#define MROWS 8192
#define DD 1024
#define DN 4096

__device__ __forceinline__ void load_lds16(const void* g, void* l) {
  __builtin_amdgcn_global_load_lds((const __attribute__((address_space(1))) void*)g,
                                   (__attribute__((address_space(3))) void*)l, 16, 0, 0);
}

// ============================================================================
// 256x256 8-phase INT8 GEMM (round-7/9 verified schedule; pipelined frag
// reads, vmcnt(6) odd phases). K bytes, K-tile=128B, NT=K>>7.
// EPI 0: h = relu(deq) -> bf16.   EPI 1: + block sum -> atomicAdd(vsum).
// ============================================================================
template<int EPI>
__global__ void __launch_bounds__(512, 1)
gemm_i8_8ph(const uint8_t* __restrict__ A, const uint8_t* __restrict__ B,
            __hip_bfloat16* __restrict__ Cb, int M, int N, int K,
            float* __restrict__ vsum,
            const float* __restrict__ sA, const float* __restrict__ sB)
{
  extern __shared__ __align__(16) char smem[];
  const int tid  = threadIdx.x;
  const int lane = tid & 63;
  const int wave = tid >> 6;
  const int wm = wave >> 2;
  const int wn = wave & 3;

  const int nwg = gridDim.x;
  const int bid = ((int)blockIdx.x % 8) * (nwg >> 3) + ((int)blockIdx.x >> 3);

  const int nbn = N >> 8;
  const int bm = (bid / nbn) << 8;
  const int bn = (bid % nbn) << 8;

  const int NT = K >> 7;

  i32x4 acc[8][4];
  const i32x4 izero = {0, 0, 0, 0};
#pragma unroll
  for (int i = 0; i < 8; ++i)
#pragma unroll
    for (int j = 0; j < 4; ++j)
      acc[i][j] = izero;

  const int csb = (((tid & 3) ^ ((tid >> 3) & 3)) << 4);
  const uint8_t* Ag = A + (size_t)(bm + (tid >> 2)) * K + csb;
  const uint8_t* Bg = B + (size_t)(bn + (tid >> 2)) * K + csb;

  const int rl = lane & 15;
  const int kc = lane >> 4;
  const int chunk_off = ((kc ^ ((rl >> 1) & 3)) << 4);
  const int aoff = ((wm << 7) + rl) * 64 + chunk_off;
  const int boff = ((wn << 6) + rl) * 64 + chunk_off;

#define STAGE_A8(S, KH) do { \
    const int kt_ = (((S) & (NT - 1)) << 7) + ((KH) << 6); \
    char* dst_ = smem + (((((S) & 1) << 1) | (KH)) << 14) + (tid << 4); \
    load_lds16(Ag + kt_, dst_); \
    load_lds16(Ag + (size_t)128 * K + kt_, dst_ + 8192); \
  } while (0)

#define STAGE_B8(S, KH) do { \
    const int kt_ = (((S) & (NT - 1)) << 7) + ((KH) << 6); \
    char* dst_ = smem + 65536 + (((((S) & 1) << 1) | (KH)) << 14) + (tid << 4); \
    load_lds16(Bg + kt_, dst_); \
    load_lds16(Bg + (size_t)128 * K + kt_, dst_ + 8192); \
  } while (0)

  i32x4 afS[2][4];
  i32x4 b0, b1, b2, b3;

#define MFMA_ROW8(MI, AF) \
    acc[MI][0] = __builtin_amdgcn_mfma_i32_16x16x64_i8(AF, b0, acc[MI][0], 0, 0, 0); \
    acc[MI][1] = __builtin_amdgcn_mfma_i32_16x16x64_i8(AF, b1, acc[MI][1], 0, 0, 0); \
    acc[MI][2] = __builtin_amdgcn_mfma_i32_16x16x64_i8(AF, b2, acc[MI][2], 0, 0, 0); \
    acc[MI][3] = __builtin_amdgcn_mfma_i32_16x16x64_i8(AF, b3, acc[MI][3], 0, 0, 0);

#define PH8(PN, KHN, MHN, ASETN, ACUR, MHC, DOBP, BP, BKH, STG, VM) do { \
    { const char* ab_ = smem + ((((PN) << 1) | (KHN)) << 14) + aoff + (MHN) * 4096; \
      afS[ASETN][0] = *(const i32x4*)(ab_); \
      afS[ASETN][1] = *(const i32x4*)(ab_ + 1024); \
      afS[ASETN][2] = *(const i32x4*)(ab_ + 2048); \
      afS[ASETN][3] = *(const i32x4*)(ab_ + 3072); } \
    STG; \
    if (VM) { asm volatile("s_waitcnt vmcnt(6)" ::: "memory"); } \
    asm volatile("s_barrier" ::: "memory"); \
    __builtin_amdgcn_sched_barrier(0); \
    __builtin_amdgcn_s_setprio(1); \
    MFMA_ROW8((MHC) * 4 + 0, afS[ACUR][0]) \
    MFMA_ROW8((MHC) * 4 + 1, afS[ACUR][1]) \
    MFMA_ROW8((MHC) * 4 + 2, afS[ACUR][2]) \
    MFMA_ROW8((MHC) * 4 + 3, afS[ACUR][3]) \
    __builtin_amdgcn_s_setprio(0); \
    if (DOBP) { \
      const char* bb_ = smem + 65536 + ((((BP) << 1) | (BKH)) << 14) + boff; \
      b0 = *(const i32x4*)(bb_); b1 = *(const i32x4*)(bb_ + 1024); \
      b2 = *(const i32x4*)(bb_ + 2048); b3 = *(const i32x4*)(bb_ + 3072); } \
    asm volatile("s_barrier" ::: "memory"); \
  } while (0)

  STAGE_A8(0, 0); STAGE_B8(0, 0);
  STAGE_A8(0, 1); STAGE_B8(0, 1);
  STAGE_A8(1, 0); STAGE_B8(1, 0);
  asm volatile("s_waitcnt vmcnt(4)" ::: "memory");
  asm volatile("s_barrier" ::: "memory");
  {
    const char* ab_ = smem + aoff;
    afS[1][0] = *(const i32x4*)(ab_);
    afS[1][1] = *(const i32x4*)(ab_ + 1024);
    afS[1][2] = *(const i32x4*)(ab_ + 2048);
    afS[1][3] = *(const i32x4*)(ab_ + 3072);
    const char* bb_ = smem + 65536 + boff;
    b0 = *(const i32x4*)(bb_); b1 = *(const i32x4*)(bb_ + 1024);
    b2 = *(const i32x4*)(bb_ + 2048); b3 = *(const i32x4*)(bb_ + 3072);
  }

#pragma unroll 1
  for (int t = 0; t < NT; t += 2) {
    PH8(0, 0, 1, 0, 1, 0, 0, 0, 0, STAGE_A8(t + 1, 1), 1);
    PH8(0, 1, 0, 1, 0, 1, 1, 0, 1, STAGE_B8(t + 1, 1), 0);
    PH8(0, 1, 1, 0, 1, 0, 0, 0, 0, STAGE_A8(t + 2, 0), 1);
    PH8(1, 0, 0, 1, 0, 1, 1, 1, 0, STAGE_B8(t + 2, 0), 0);
    PH8(1, 0, 1, 0, 1, 0, 0, 0, 0, STAGE_A8(t + 2, 1), 1);
    PH8(1, 1, 0, 1, 0, 1, 1, 1, 1, STAGE_B8(t + 2, 1), 0);
    PH8(1, 1, 1, 0, 1, 0, 0, 0, 0, STAGE_A8(t + 3, 0), 1);
    PH8(0, 0, 0, 1, 0, 1, 1, 0, 0, STAGE_B8(t + 3, 0), 0);
  }

  const int r0 = bm + (wm << 7) + (kc << 2);
  const int c0 = bn + (wn << 6) + rl;
  float lsum = 0.f;
#pragma unroll
  for (int mi = 0; mi < 8; ++mi) {
#pragma unroll
    for (int nf = 0; nf < 4; ++nf) {
#pragma unroll
      for (int q = 0; q < 4; ++q) {
        const int r = r0 + (mi << 4) + q;
        const int c = c0 + (nf << 4);
        float v = (float)acc[mi][nf][q] * sA[r] * sB[c];
        v = fmaxf(v, 0.f);
        Cb[(size_t)r * N + c] = __float2bfloat16(v);
        if constexpr (EPI == 1) lsum += v;
      }
    }
  }
  if constexpr (EPI == 1) {
#pragma unroll
    for (int off = 32; off > 0; off >>= 1)
      lsum += __shfl_down(lsum, off);
    if (lane == 0) atomicAdd(vsum, lsum);
  }

#undef STAGE_A8
#undef STAGE_B8
#undef MFMA_ROW8
#undef PH8
}

// ============================================================================
// Fused pred+gate, 128x128 2-barrier INT8 (round-8 verified):
//   acc1 = spq @ wuq^T (K1=4096) ; acc2 = xq @ wgq^T (K2=1024)
//   out  = x + sigmoid(acc2*sx[r]*swg[c] + bgate[c]) * (acc1*sA[r]*swu[c])
// ============================================================================
__global__ void __launch_bounds__(256)
gemm_predgate(const uint8_t* __restrict__ Asp, const uint8_t* __restrict__ Bup,
              const uint8_t* __restrict__ Ax,  const uint8_t* __restrict__ Bg8,
              float* __restrict__ Cf, int M, int N, int K1, int K2,
              const float* __restrict__ sA,  const float* __restrict__ swu,
              const float* __restrict__ sx,  const float* __restrict__ swg,
              const float* __restrict__ Xf,  const float* __restrict__ Bgate)
{
  __shared__ __align__(16) char smem[32768];
  const int tid  = threadIdx.x;
  const int lane = tid & 63;
  const int wave = tid >> 6;

  const int nbn = N >> 7;
  const int bm = ((int)blockIdx.x / nbn) << 7;
  const int bn = ((int)blockIdx.x % nbn) << 7;

  const int wm = (wave >> 1) << 6;
  const int wn = (wave & 1) << 6;

  i32x4 acc1[4][4], acc2[4][4];
  const i32x4 izero = {0, 0, 0, 0};
#pragma unroll
  for (int i = 0; i < 4; ++i)
#pragma unroll
    for (int j = 0; j < 4; ++j) { acc1[i][j] = izero; acc2[i][j] = izero; }

  const int srow = tid >> 3;
  const int schk = (tid & 7) ^ (srow & 7);
  char* ldsA = smem + (wave << 10);
  char* ldsB = smem + 16384 + (wave << 10);

  const int aoff0 = (wm + (lane & 15)) << 7;
  const int boff0 = 16384 + ((wn + (lane & 15)) << 7);
  const int kc = lane >> 4;
  const int sw = lane & 7;

#define K_LOOP(APTR, BPTR, KK, ACC) do { \
    const uint8_t* Ag = (APTR) + (size_t)(bm + srow) * (KK) + (schk << 4); \
    const uint8_t* Bg = (BPTR) + (size_t)(bn + srow) * (KK) + (schk << 4); \
    for (int k0 = 0; k0 < (KK); k0 += 128) { \
      _Pragma("unroll") \
      for (int i = 0; i < 4; ++i) \
        load_lds16(Ag + (size_t)(i << 5) * (KK) + k0, ldsA + (i << 12)); \
      _Pragma("unroll") \
      for (int i = 0; i < 4; ++i) \
        load_lds16(Bg + (size_t)(i << 5) * (KK) + k0, ldsB + (i << 12)); \
      __syncthreads(); \
      _Pragma("unroll") \
      for (int ks = 0; ks < 2; ++ks) { \
        const int cb = ((kc + (ks << 2)) ^ sw) << 4; \
        i32x4 af[4], bfr[4]; \
        _Pragma("unroll") \
        for (int i = 0; i < 4; ++i) \
          af[i] = *reinterpret_cast<const i32x4*>(smem + aoff0 + (i << 11) + cb); \
        _Pragma("unroll") \
        for (int j = 0; j < 4; ++j) \
          bfr[j] = *reinterpret_cast<const i32x4*>(smem + boff0 + (j << 11) + cb); \
        _Pragma("unroll") \
        for (int i = 0; i < 4; ++i) \
          _Pragma("unroll") \
          for (int j = 0; j < 4; ++j) \
            ACC[i][j] = __builtin_amdgcn_mfma_i32_16x16x64_i8(af[i], bfr[j], ACC[i][j], 0, 0, 0); \
      } \
      __syncthreads(); \
    } \
  } while (0)

  K_LOOP(Asp, Bup, K1, acc1);
  K_LOOP(Ax,  Bg8, K2, acc2);
#undef K_LOOP

  const int r0 = bm + wm + ((lane >> 4) << 2);
  const int c0 = bn + wn + (lane & 15);
#pragma unroll
  for (int i = 0; i < 4; ++i) {
#pragma unroll
    for (int j = 0; j < 4; ++j) {
#pragma unroll
      for (int q = 0; q < 4; ++q) {
        const int r = r0 + (i << 4) + q;
        const int c = c0 + (j << 4);
        const size_t idx = (size_t)r * N + c;
        const float pred = (float)acc1[i][j][q] * sA[r] * swu[c];
        const float vg   = (float)acc2[i][j][q] * sx[r] * swg[c] + Bgate[c];
        const float g = 1.f / (1.f + __expf(-vg));
        Cf[idx] = Xf[idx] + g * pred;
      }
    }
  }
}

// ============================================================================
// kwta, wave-per-row (round-7 verified). Exact threshold via 16-step binary
// search on u16 bf16 keys (nonneg). Emits INT8 normalized row + scale:
// q = rint(v/vmax*127) kept else 0 ; sA = vmax*inv/127 so q*sA = v*inv.
// MODE 0: always write.  MODE 1: only when *vsumPtr >= EPS (else keep old).
// ============================================================================
template<int MODE>
__global__ void __launch_bounds__(256)
kwta_wave(const __hip_bfloat16* __restrict__ H, uint8_t* __restrict__ OUTQ,
          float* __restrict__ sA, const float* __restrict__ vsumPtr,
          const int* __restrict__ kptr)
{
  const int tid  = threadIdx.x;
  const int lane = tid & 63;
  const int w    = tid >> 6;
  const int row  = ((int)blockIdx.x << 2) + w;

  if constexpr (MODE == 1) {
    if (!(*vsumPtr >= 1e-10f)) return;
  }

  const uint4* h8 = (const uint4*)(H + (size_t)row * 4096);
  uint4 d[8];
#pragma unroll
  for (int i = 0; i < 8; ++i) d[i] = h8[(i << 6) + lane];

  const unsigned k = (unsigned)(*kptr);

  unsigned kmax = 0;
#pragma unroll
  for (int i = 0; i < 8; ++i) {
    const unsigned* p = (const unsigned*)&d[i];
#pragma unroll
    for (int c4 = 0; c4 < 4; ++c4) {
      kmax = max(kmax, p[c4] & 0xffffu);
      kmax = max(kmax, p[c4] >> 16);
    }
  }
#pragma unroll
  for (int off = 32; off > 0; off >>= 1) kmax = max(kmax, __shfl_xor(kmax, off));

  unsigned lo = 0, hi = 65536;
#pragma unroll 1
  for (int it = 0; it < 16; ++it) {
    const unsigned mid = (lo + hi) >> 1;
    unsigned c = 0;
#pragma unroll
    for (int i = 0; i < 8; ++i) {
      const unsigned* p = (const unsigned*)&d[i];
#pragma unroll
      for (int c4 = 0; c4 < 4; ++c4) {
        c += ((p[c4] & 0xffffu) >= mid) ? 1u : 0u;
        c += ((p[c4] >> 16) >= mid) ? 1u : 0u;
      }
    }
#pragma unroll
    for (int off = 32; off > 0; off >>= 1) c += __shfl_xor(c, off);
    if (c >= k) lo = mid; else hi = mid;
  }
  const unsigned threshKey = lo;

  float ss = 0.f;
#pragma unroll
  for (int i = 0; i < 8; ++i) {
    const unsigned* p = (const unsigned*)&d[i];
#pragma unroll
    for (int c4 = 0; c4 < 4; ++c4) {
#pragma unroll
      for (int hh = 0; hh < 2; ++hh) {
        const unsigned key = hh ? (p[c4] >> 16) : (p[c4] & 0xffffu);
        if (key >= threshKey) {
          const float v = __uint_as_float(key << 16);
          ss = fmaf(v, v, ss);
        }
      }
    }
  }
#pragma unroll
  for (int off = 32; off > 0; off >>= 1) ss += __shfl_xor(ss, off);
  const float inv = 1.f / fmaxf(sqrtf(ss), 1e-10f);

  const float vmaxf = __uint_as_float(kmax << 16);
  const float r127 = (kmax > 0) ? 127.f / vmaxf : 0.f;

  if (lane == 0) sA[row] = vmaxf * inv * (1.f / 127.f);

  uint2* o2 = (uint2*)(OUTQ + (size_t)row * 4096);
#pragma unroll
  for (int i = 0; i < 8; ++i) {
    const unsigned* p = (const unsigned*)&d[i];
    unsigned b[8];
#pragma unroll
    for (int c4 = 0; c4 < 4; ++c4) {
#pragma unroll
      for (int hh = 0; hh < 2; ++hh) {
        const unsigned key = hh ? (p[c4] >> 16) : (p[c4] & 0xffffu);
        unsigned q = 0;
        if (key >= threshKey && key > 0) {
          const float v = __uint_as_float(key << 16);
          q = (unsigned)__float2int_rn(v * r127) & 0xffu;
        }
        b[c4 * 2 + hh] = q;
      }
    }
    uint2 o;
    o.x = b[0] | (b[1] << 8) | (b[2] << 16) | (b[3] << 24);
    o.y = b[4] | (b[5] << 8) | (b[6] << 16) | (b[7] << 24);
    o2[(i << 6) + lane] = o;
  }
}

// ============================================================================
// Per-row quantization (verified): K=1024 rows for x / W_down / W_gate.
// ============================================================================
__global__ void __launch_bounds__(256)
quant1024(const float* __restrict__ X, const float* __restrict__ Wd,
          const float* __restrict__ Wg,
          uint8_t* __restrict__ xq, uint8_t* __restrict__ wdq,
          uint8_t* __restrict__ wgq,
          float* __restrict__ sx, float* __restrict__ swd,
          float* __restrict__ swg)
{
  const int wgl = ((int)blockIdx.x << 2) + (threadIdx.x >> 6);
  const int lane = threadIdx.x & 63;

  const float* W; uint8_t* q; float* s; int row;
  if      (wgl < 8192)  { W = X;  q = xq;  s = sx;  row = wgl; }
  else if (wgl < 12288) { W = Wd; q = wdq; s = swd; row = wgl - 8192; }
  else                  { W = Wg; q = wgq; s = swg; row = wgl - 12288; }

  const float4* src = (const float4*)(W + (size_t)row * 1024);
  float4 v[4];
  float am = 0.f;
#pragma unroll
  for (int i = 0; i < 4; ++i) {
    v[i] = src[(i << 6) + lane];
    am = fmaxf(am, fmaxf(fmaxf(fabsf(v[i].x), fabsf(v[i].y)),
                         fmaxf(fabsf(v[i].z), fabsf(v[i].w))));
  }
#pragma unroll
  for (int off = 32; off > 0; off >>= 1) am = fmaxf(am, __shfl_xor(am, off));

  const float rinv = (am > 0.f) ? 127.f / am : 0.f;
  uint4 o;
  unsigned* ob = (unsigned*)&o;
#pragma unroll
  for (int i = 0; i < 4; ++i) {
    const unsigned b0 = (unsigned)__float2int_rn(v[i].x * rinv) & 0xffu;
    const unsigned b1 = (unsigned)__float2int_rn(v[i].y * rinv) & 0xffu;
    const unsigned b2 = (unsigned)__float2int_rn(v[i].z * rinv) & 0xffu;
    const unsigned b3 = (unsigned)__float2int_rn(v[i].w * rinv) & 0xffu;
    ob[i] = b0 | (b1 << 8) | (b2 << 16) | (b3 << 24);
  }
  ((uint4*)(q + (size_t)row * 1024))[lane] = o;
  if (lane == 0) s[row] = am * (1.f / 127.f);
}

// Per-row quantization, K=4096: W_ca3 (4096 rows) / W_up (1024 rows).
__global__ void __launch_bounds__(256)
quant4096(const float* __restrict__ Wc, const float* __restrict__ Wu,
          uint8_t* __restrict__ qc, uint8_t* __restrict__ qu,
          float* __restrict__ sc, float* __restrict__ su)
{
  const int wgl = ((int)blockIdx.x << 2) + (threadIdx.x >> 6);
  const int lane = threadIdx.x & 63;

  const float* W; uint8_t* q; float* s; int row;
  if (wgl < 4096) { W = Wc; q = qc; s = sc; row = wgl; }
  else            { W = Wu; q = qu; s = su; row = wgl - 4096; }

  const float4* src = (const float4*)(W + (size_t)row * 4096);
  float4 v[16];
  float am = 0.f;
#pragma unroll
  for (int i = 0; i < 16; ++i) {
    v[i] = src[(i << 6) + lane];
    am = fmaxf(am, fmaxf(fmaxf(fabsf(v[i].x), fabsf(v[i].y)),
                         fmaxf(fabsf(v[i].z), fabsf(v[i].w))));
  }
#pragma unroll
  for (int off = 32; off > 0; off >>= 1) am = fmaxf(am, __shfl_xor(am, off));

  const float rinv = (am > 0.f) ? 127.f / am : 0.f;
  unsigned* qo = (unsigned*)(q + (size_t)row * 4096);
#pragma unroll
  for (int i = 0; i < 16; ++i) {
    const unsigned b0 = (unsigned)__float2int_rn(v[i].x * rinv) & 0xffu;
    const unsigned b1 = (unsigned)__float2int_rn(v[i].y * rinv) & 0xffu;
    const unsigned b2 = (unsigned)__float2int_rn(v[i].z * rinv) & 0xffu;
    const unsigned b3 = (unsigned)__float2int_rn(v[i].w * rinv) & 0xffu;
    qo[(i << 6) + lane] = b0 | (b1 << 8) | (b2 << 16) | (b3 << 24);
  }
  if (lane == 0) s[row] = am * (1.f / 127.f);
}

__global__ void diag_kernel(float* out, float mb)
{
  if (threadIdx.x == 0 && blockIdx.x == 0) out[0] = -mb;
}

extern "C" void kernel_launch(void* const* d_in, const int* in_sizes, int n_in,
                              void* d_out, int out_size, void* d_ws, size_t ws_size,
                              hipStream_t stream)
{
  const float* x     = (const float*)d_in[0]; // (8192,1024)
  const float* Wdown = (const float*)d_in[1]; // (4096,1024)
  const float* Wup   = (const float*)d_in[2]; // (1024,4096)
  const float* Wgate = (const float*)d_in[3]; // (1024,1024)
  const float* bgate = (const float*)d_in[4]; // (1024,)
  const float* Wca3  = (const float*)d_in[5]; // (4096,4096)
  const int*   kptr  = (const int*)d_in[6];

  const size_t OFF_XQ   = 0;         //  8 MB i8 x
  const size_t OFF_WDQ  = 8388608;   //  4 MB i8 W_down
  const size_t OFF_WGQ  = 12582912;  //  1 MB i8 W_gate
  const size_t OFF_WCQ  = 13631488;  // 16 MB i8 W_ca3
  const size_t OFF_WUQ  = 30408704;  //  4 MB i8 W_up
  const size_t OFF_SX   = 34603008;  // 32 KB
  const size_t OFF_SWD  = 34635776;  // 16 KB
  const size_t OFF_SWG  = 34652160;  //  4 KB
  const size_t OFF_SWC  = 34656256;  // 16 KB
  const size_t OFF_SWU  = 34672640;  //  4 KB
  const size_t OFF_SA   = 34676736;  // 32 KB
  const size_t OFF_VSUM = 34709504;  //  4 KB pad
  const size_t OFF_SPQ  = 34713600;  // 32 MB i8 sparse/successor
  const size_t OFF_H    = 68268032;  // 64 MB bf16 h1/h2
  const size_t NEED     = 135376896;

  if (ws_size < NEED) {
    diag_kernel<<<1, 64, 0, stream>>>((float*)d_out, (float)(ws_size >> 20));
    return;
  }

  char* ws = (char*)d_ws;
  uint8_t*        xq   = (uint8_t*)       (ws + OFF_XQ);
  uint8_t*        wdq  = (uint8_t*)       (ws + OFF_WDQ);
  uint8_t*        wgq  = (uint8_t*)       (ws + OFF_WGQ);
  uint8_t*        wcq  = (uint8_t*)       (ws + OFF_WCQ);
  uint8_t*        wuq  = (uint8_t*)       (ws + OFF_WUQ);
  float*          sx   = (float*)         (ws + OFF_SX);
  float*          swd  = (float*)         (ws + OFF_SWD);
  float*          swg  = (float*)         (ws + OFF_SWG);
  float*          swc  = (float*)         (ws + OFF_SWC);
  float*          swu  = (float*)         (ws + OFF_SWU);
  float*          sA   = (float*)         (ws + OFF_SA);
  float*          vsum = (float*)         (ws + OFF_VSUM);
  uint8_t*        spq  = (uint8_t*)       (ws + OFF_SPQ);
  __hip_bfloat16* h    = (__hip_bfloat16*)(ws + OFF_H);

  hipMemsetAsync(vsum, 0, sizeof(float), stream);

  // quantize inputs/weights to i8 with per-row scales
  quant1024<<<3328, 256, 0, stream>>>(x, Wdown, Wgate, xq, wdq, wgq, sx, swd, swg);
  quant4096<<<1280, 256, 0, stream>>>(Wca3, Wup, wcq, wuq, swc, swu);

  // h1 = relu(sx*swd * (xq @ wdq^T)) -> bf16   [i8 8-phase 256^2, grid 512]
  gemm_i8_8ph<0><<<(MROWS >> 8) * (DN >> 8), 512, 131072, stream>>>(
      xq, wdq, h, MROWS, DN, DD, nullptr, sx, swd);
  // sparse = kwta(h1)/norm -> i8 + scale
  kwta_wave<0><<<MROWS / 4, 256, 0, stream>>>(h, spq, sA, nullptr, kptr);
  // h2 = relu(sA*swc * (spq @ wcq^T)) -> bf16, sum -> vsum   [i8 8-phase]
  gemm_i8_8ph<1><<<(MROWS >> 8) * (DN >> 8), 512, 131072, stream>>>(
      spq, wcq, h, MROWS, DN, DN, vsum, sA, swc);
  // successor = valid ? kwta(h2)/norm : sparse (i8 + scale, in-place)
  kwta_wave<1><<<MROWS / 4, 256, 0, stream>>>(h, spq, sA, vsum, kptr);
  // out = x + sigmoid(xq@wgq^T deq + b) * (spq@wuq^T deq)   [fused 128^2]
  gemm_predgate<<<(MROWS >> 7) * (DD >> 7), 256, 0, stream>>>(
      spq, wuq, xq, wgq, (float*)d_out, MROWS, DD, DN, DD,
      sA, swu, sx, swg, x, bgate);
}

// Round 11
// 406.312 us; speedup vs baseline: 1.3766x; 1.1260x over previous
//
#include <hip/hip_runtime.h>
#include <hip/hip_bf16.h>
#include <stdint.h>

typedef float f32x4 __attribute__((ext_vector_type(4)));
typedef int i32x4 __attribute__((ext_vector_type(4)));

#define MROWS 8192
#define DD 1024
#define DN 4096

__device__ __forceinline__ void load_lds16(const void* g, void* l) {
  __builtin_amdgcn_global_load_lds((const __attribute__((address_space(1))) void*)g,
                                   (__attribute__((address_space(3))) void*)l, 16, 0, 0);
}

// ============================================================================
// 256x256 8-phase INT8 GEMM (round-7/9/10 verified schedule; pipelined frag
// reads, vmcnt(6) odd phases). K bytes, K-tile=128B, NT=K>>7.
// EPI 0: h = relu(deq) -> bf16.   EPI 1: + block sum -> atomicAdd(vsum).
// ============================================================================
template<int EPI>
__global__ void __launch_bounds__(512, 1)
gemm_i8_8ph(const uint8_t* __restrict__ A, const uint8_t* __restrict__ B,
            __hip_bfloat16* __restrict__ Cb, int M, int N, int K,
            float* __restrict__ vsum,
            const float* __restrict__ sA, const float* __restrict__ sB)
{
  extern __shared__ __align__(16) char smem[];
  const int tid  = threadIdx.x;
  const int lane = tid & 63;
  const int wave = tid >> 6;
  const int wm = wave >> 2;
  const int wn = wave & 3;

  const int nwg = gridDim.x;
  const int bid = ((int)blockIdx.x % 8) * (nwg >> 3) + ((int)blockIdx.x >> 3);

  const int nbn = N >> 8;
  const int bm = (bid / nbn) << 8;
  const int bn = (bid % nbn) << 8;

  const int NT = K >> 7;

  i32x4 acc[8][4];
  const i32x4 izero = {0, 0, 0, 0};
#pragma unroll
  for (int i = 0; i < 8; ++i)
#pragma unroll
    for (int j = 0; j < 4; ++j)
      acc[i][j] = izero;

  const int csb = (((tid & 3) ^ ((tid >> 3) & 3)) << 4);
  const uint8_t* Ag = A + (size_t)(bm + (tid >> 2)) * K + csb;
  const uint8_t* Bg = B + (size_t)(bn + (tid >> 2)) * K + csb;

  const int rl = lane & 15;
  const int kc = lane >> 4;
  const int chunk_off = ((kc ^ ((rl >> 1) & 3)) << 4);
  const int aoff = ((wm << 7) + rl) * 64 + chunk_off;
  const int boff = ((wn << 6) + rl) * 64 + chunk_off;

#define STAGE_A8(S, KH) do { \
    const int kt_ = (((S) & (NT - 1)) << 7) + ((KH) << 6); \
    char* dst_ = smem + (((((S) & 1) << 1) | (KH)) << 14) + (tid << 4); \
    load_lds16(Ag + kt_, dst_); \
    load_lds16(Ag + (size_t)128 * K + kt_, dst_ + 8192); \
  } while (0)

#define STAGE_B8(S, KH) do { \
    const int kt_ = (((S) & (NT - 1)) << 7) + ((KH) << 6); \
    char* dst_ = smem + 65536 + (((((S) & 1) << 1) | (KH)) << 14) + (tid << 4); \
    load_lds16(Bg + kt_, dst_); \
    load_lds16(Bg + (size_t)128 * K + kt_, dst_ + 8192); \
  } while (0)

  i32x4 afS[2][4];
  i32x4 b0, b1, b2, b3;

#define MFMA_ROW8(MI, AF) \
    acc[MI][0] = __builtin_amdgcn_mfma_i32_16x16x64_i8(AF, b0, acc[MI][0], 0, 0, 0); \
    acc[MI][1] = __builtin_amdgcn_mfma_i32_16x16x64_i8(AF, b1, acc[MI][1], 0, 0, 0); \
    acc[MI][2] = __builtin_amdgcn_mfma_i32_16x16x64_i8(AF, b2, acc[MI][2], 0, 0, 0); \
    acc[MI][3] = __builtin_amdgcn_mfma_i32_16x16x64_i8(AF, b3, acc[MI][3], 0, 0, 0);

#define PH8(PN, KHN, MHN, ASETN, ACUR, MHC, DOBP, BP, BKH, STG, VM) do { \
    { const char* ab_ = smem + ((((PN) << 1) | (KHN)) << 14) + aoff + (MHN) * 4096; \
      afS[ASETN][0] = *(const i32x4*)(ab_); \
      afS[ASETN][1] = *(const i32x4*)(ab_ + 1024); \
      afS[ASETN][2] = *(const i32x4*)(ab_ + 2048); \
      afS[ASETN][3] = *(const i32x4*)(ab_ + 3072); } \
    STG; \
    if (VM) { asm volatile("s_waitcnt vmcnt(6)" ::: "memory"); } \
    asm volatile("s_barrier" ::: "memory"); \
    __builtin_amdgcn_sched_barrier(0); \
    __builtin_amdgcn_s_setprio(1); \
    MFMA_ROW8((MHC) * 4 + 0, afS[ACUR][0]) \
    MFMA_ROW8((MHC) * 4 + 1, afS[ACUR][1]) \
    MFMA_ROW8((MHC) * 4 + 2, afS[ACUR][2]) \
    MFMA_ROW8((MHC) * 4 + 3, afS[ACUR][3]) \
    __builtin_amdgcn_s_setprio(0); \
    if (DOBP) { \
      const char* bb_ = smem + 65536 + ((((BP) << 1) | (BKH)) << 14) + boff; \
      b0 = *(const i32x4*)(bb_); b1 = *(const i32x4*)(bb_ + 1024); \
      b2 = *(const i32x4*)(bb_ + 2048); b3 = *(const i32x4*)(bb_ + 3072); } \
    asm volatile("s_barrier" ::: "memory"); \
  } while (0)

  STAGE_A8(0, 0); STAGE_B8(0, 0);
  STAGE_A8(0, 1); STAGE_B8(0, 1);
  STAGE_A8(1, 0); STAGE_B8(1, 0);
  asm volatile("s_waitcnt vmcnt(4)" ::: "memory");
  asm volatile("s_barrier" ::: "memory");
  {
    const char* ab_ = smem + aoff;
    afS[1][0] = *(const i32x4*)(ab_);
    afS[1][1] = *(const i32x4*)(ab_ + 1024);
    afS[1][2] = *(const i32x4*)(ab_ + 2048);
    afS[1][3] = *(const i32x4*)(ab_ + 3072);
    const char* bb_ = smem + 65536 + boff;
    b0 = *(const i32x4*)(bb_); b1 = *(const i32x4*)(bb_ + 1024);
    b2 = *(const i32x4*)(bb_ + 2048); b3 = *(const i32x4*)(bb_ + 3072);
  }

#pragma unroll 1
  for (int t = 0; t < NT; t += 2) {
    PH8(0, 0, 1, 0, 1, 0, 0, 0, 0, STAGE_A8(t + 1, 1), 1);
    PH8(0, 1, 0, 1, 0, 1, 1, 0, 1, STAGE_B8(t + 1, 1), 0);
    PH8(0, 1, 1, 0, 1, 0, 0, 0, 0, STAGE_A8(t + 2, 0), 1);
    PH8(1, 0, 0, 1, 0, 1, 1, 1, 0, STAGE_B8(t + 2, 0), 0);
    PH8(1, 0, 1, 0, 1, 0, 0, 0, 0, STAGE_A8(t + 2, 1), 1);
    PH8(1, 1, 0, 1, 0, 1, 1, 1, 1, STAGE_B8(t + 2, 1), 0);
    PH8(1, 1, 1, 0, 1, 0, 0, 0, 0, STAGE_A8(t + 3, 0), 1);
    PH8(0, 0, 0, 1, 0, 1, 1, 0, 0, STAGE_B8(t + 3, 0), 0);
  }

  const int r0 = bm + (wm << 7) + (kc << 2);
  const int c0 = bn + (wn << 6) + rl;
  float lsum = 0.f;
#pragma unroll
  for (int mi = 0; mi < 8; ++mi) {
#pragma unroll
    for (int nf = 0; nf < 4; ++nf) {
#pragma unroll
      for (int q = 0; q < 4; ++q) {
        const int r = r0 + (mi << 4) + q;
        const int c = c0 + (nf << 4);
        float v = (float)acc[mi][nf][q] * sA[r] * sB[c];
        v = fmaxf(v, 0.f);
        Cb[(size_t)r * N + c] = __float2bfloat16(v);
        if constexpr (EPI == 1) lsum += v;
      }
    }
  }
  if constexpr (EPI == 1) {
#pragma unroll
    for (int off = 32; off > 0; off >>= 1)
      lsum += __shfl_down(lsum, off);
    if (lane == 0) atomicAdd(vsum, lsum);
  }

#undef STAGE_A8
#undef STAGE_B8
#undef MFMA_ROW8
#undef PH8
}

// ============================================================================
// 128x128 2-barrier INT8 GEMM (round-7 verified) + XCD swizzle — pred:
// pred = (spq @ wuq^T) * sA[r] * sB[c] -> bf16 (no relu).
// ============================================================================
__global__ void __launch_bounds__(256)
gemm_i8_128(const uint8_t* __restrict__ A, const uint8_t* __restrict__ B,
            __hip_bfloat16* __restrict__ Cb, int M, int N, int K,
            const float* __restrict__ sA, const float* __restrict__ sB)
{
  __shared__ __align__(16) char smem[32768];
  const int tid  = threadIdx.x;
  const int lane = tid & 63;
  const int wave = tid >> 6;

  const int nwg = gridDim.x;
  const int bid = ((int)blockIdx.x % 8) * (nwg >> 3) + ((int)blockIdx.x >> 3);

  const int nbn = N >> 7;
  const int bm = (bid / nbn) << 7;
  const int bn = (bid % nbn) << 7;

  const int wm = (wave >> 1) << 6;
  const int wn = (wave & 1) << 6;

  i32x4 acc[4][4];
  const i32x4 izero = {0, 0, 0, 0};
#pragma unroll
  for (int i = 0; i < 4; ++i)
#pragma unroll
    for (int j = 0; j < 4; ++j)
      acc[i][j] = izero;

  const int srow = tid >> 3;
  const int schk = (tid & 7) ^ (srow & 7);
  const uint8_t* Ag = A + (size_t)(bm + srow) * K + (schk << 4);
  const uint8_t* Bg = B + (size_t)(bn + srow) * K + (schk << 4);
  char* ldsA = smem + (wave << 10);
  char* ldsB = smem + 16384 + (wave << 10);

  const int aoff0 = (wm + (lane & 15)) << 7;
  const int boff0 = 16384 + ((wn + (lane & 15)) << 7);
  const int kc = lane >> 4;
  const int sw = lane & 7;

  for (int k0 = 0; k0 < K; k0 += 128) {
#pragma unroll
    for (int i = 0; i < 4; ++i)
      load_lds16(Ag + (size_t)(i << 5) * K + k0, ldsA + (i << 12));
#pragma unroll
    for (int i = 0; i < 4; ++i)
      load_lds16(Bg + (size_t)(i << 5) * K + k0, ldsB + (i << 12));
    __syncthreads();
#pragma unroll
    for (int ks = 0; ks < 2; ++ks) {
      const int cb = ((kc + (ks << 2)) ^ sw) << 4;
      i32x4 af[4], bfr[4];
#pragma unroll
      for (int i = 0; i < 4; ++i)
        af[i] = *reinterpret_cast<const i32x4*>(smem + aoff0 + (i << 11) + cb);
#pragma unroll
      for (int j = 0; j < 4; ++j)
        bfr[j] = *reinterpret_cast<const i32x4*>(smem + boff0 + (j << 11) + cb);
#pragma unroll
      for (int i = 0; i < 4; ++i)
#pragma unroll
        for (int j = 0; j < 4; ++j)
          acc[i][j] = __builtin_amdgcn_mfma_i32_16x16x64_i8(af[i], bfr[j], acc[i][j], 0, 0, 0);
    }
    __syncthreads();
  }

  const int r0 = bm + wm + ((lane >> 4) << 2);
  const int c0 = bn + wn + (lane & 15);
#pragma unroll
  for (int i = 0; i < 4; ++i)
#pragma unroll
    for (int j = 0; j < 4; ++j)
#pragma unroll
      for (int q = 0; q < 4; ++q) {
        const int r = r0 + (i << 4) + q;
        const int c = c0 + (j << 4);
        Cb[(size_t)r * N + c] =
            __float2bfloat16((float)acc[i][j][q] * sA[r] * sB[c]);
      }
}

// ============================================================================
// 128x128 2-barrier INT8 gate GEMM + fused final epilogue (round-7 shape):
// out = x + sigmoid(deq(xq@wgq^T) + bgate) * pred(bf16)   (f32 out)
// ============================================================================
__global__ void __launch_bounds__(256)
gemm_gate_i8(const uint8_t* __restrict__ A, const uint8_t* __restrict__ B,
             float* __restrict__ Cf, int M, int N, int K,
             const float* __restrict__ sA, const float* __restrict__ sB,
             const float* __restrict__ Xf, const __hip_bfloat16* __restrict__ PredBf,
             const float* __restrict__ Bgate)
{
  __shared__ __align__(16) char smem[32768];
  const int tid  = threadIdx.x;
  const int lane = tid & 63;
  const int wave = tid >> 6;

  const int nwg = gridDim.x;
  const int bid = ((int)blockIdx.x % 8) * (nwg >> 3) + ((int)blockIdx.x >> 3);

  const int nbn = N >> 7;
  const int bm = (bid / nbn) << 7;
  const int bn = (bid % nbn) << 7;

  const int wm = (wave >> 1) << 6;
  const int wn = (wave & 1) << 6;

  i32x4 acc[4][4];
  const i32x4 izero = {0, 0, 0, 0};
#pragma unroll
  for (int i = 0; i < 4; ++i)
#pragma unroll
    for (int j = 0; j < 4; ++j) acc[i][j] = izero;

  const int srow = tid >> 3;
  const int schk = (tid & 7) ^ (srow & 7);
  const uint8_t* Ag = A + (size_t)(bm + srow) * K + (schk << 4);
  const uint8_t* Bg = B + (size_t)(bn + srow) * K + (schk << 4);
  char* ldsA = smem + (wave << 10);
  char* ldsB = smem + 16384 + (wave << 10);

  const int aoff0 = (wm + (lane & 15)) << 7;
  const int boff0 = 16384 + ((wn + (lane & 15)) << 7);
  const int kc = lane >> 4;
  const int sw = lane & 7;

  for (int k0 = 0; k0 < K; k0 += 128) {
#pragma unroll
    for (int i = 0; i < 4; ++i)
      load_lds16(Ag + (size_t)(i << 5) * K + k0, ldsA + (i << 12));
#pragma unroll
    for (int i = 0; i < 4; ++i)
      load_lds16(Bg + (size_t)(i << 5) * K + k0, ldsB + (i << 12));
    __syncthreads();
#pragma unroll
    for (int ks = 0; ks < 2; ++ks) {
      const int cb = ((kc + (ks << 2)) ^ sw) << 4;
      i32x4 af[4], bfr[4];
#pragma unroll
      for (int i = 0; i < 4; ++i)
        af[i] = *reinterpret_cast<const i32x4*>(smem + aoff0 + (i << 11) + cb);
#pragma unroll
      for (int j = 0; j < 4; ++j)
        bfr[j] = *reinterpret_cast<const i32x4*>(smem + boff0 + (j << 11) + cb);
#pragma unroll
      for (int i = 0; i < 4; ++i)
#pragma unroll
        for (int j = 0; j < 4; ++j)
          acc[i][j] = __builtin_amdgcn_mfma_i32_16x16x64_i8(af[i], bfr[j], acc[i][j], 0, 0, 0);
    }
    __syncthreads();
  }

  const int r0 = bm + wm + ((lane >> 4) << 2);
  const int c0 = bn + wn + (lane & 15);
#pragma unroll
  for (int i = 0; i < 4; ++i)
#pragma unroll
    for (int j = 0; j < 4; ++j)
#pragma unroll
      for (int q = 0; q < 4; ++q) {
        const int r = r0 + (i << 4) + q;
        const int c = c0 + (j << 4);
        const size_t idx = (size_t)r * N + c;
        const float vg = (float)acc[i][j][q] * sA[r] * sB[c] + Bgate[c];
        const float g = 1.f / (1.f + __expf(-vg));
        Cf[idx] = Xf[idx] + g * __bfloat162float(PredBf[idx]);
      }
}

// ============================================================================
// kwta, wave-per-row (round-7 verified). Exact threshold via 16-step binary
// search on u16 bf16 keys (nonneg). Emits INT8 normalized row + scale.
// MODE 0: always write.  MODE 1: only when *vsumPtr >= EPS (else keep old).
// ============================================================================
template<int MODE>
__global__ void __launch_bounds__(256)
kwta_wave(const __hip_bfloat16* __restrict__ H, uint8_t* __restrict__ OUTQ,
          float* __restrict__ sA, const float* __restrict__ vsumPtr,
          const int* __restrict__ kptr)
{
  const int tid  = threadIdx.x;
  const int lane = tid & 63;
  const int w    = tid >> 6;
  const int row  = ((int)blockIdx.x << 2) + w;

  if constexpr (MODE == 1) {
    if (!(*vsumPtr >= 1e-10f)) return;
  }

  const uint4* h8 = (const uint4*)(H + (size_t)row * 4096);
  uint4 d[8];
#pragma unroll
  for (int i = 0; i < 8; ++i) d[i] = h8[(i << 6) + lane];

  const unsigned k = (unsigned)(*kptr);

  unsigned kmax = 0;
#pragma unroll
  for (int i = 0; i < 8; ++i) {
    const unsigned* p = (const unsigned*)&d[i];
#pragma unroll
    for (int c4 = 0; c4 < 4; ++c4) {
      kmax = max(kmax, p[c4] & 0xffffu);
      kmax = max(kmax, p[c4] >> 16);
    }
  }
#pragma unroll
  for (int off = 32; off > 0; off >>= 1) kmax = max(kmax, __shfl_xor(kmax, off));

  unsigned lo = 0, hi = 65536;
#pragma unroll 1
  for (int it = 0; it < 16; ++it) {
    const unsigned mid = (lo + hi) >> 1;
    unsigned c = 0;
#pragma unroll
    for (int i = 0; i < 8; ++i) {
      const unsigned* p = (const unsigned*)&d[i];
#pragma unroll
      for (int c4 = 0; c4 < 4; ++c4) {
        c += ((p[c4] & 0xffffu) >= mid) ? 1u : 0u;
        c += ((p[c4] >> 16) >= mid) ? 1u : 0u;
      }
    }
#pragma unroll
    for (int off = 32; off > 0; off >>= 1) c += __shfl_xor(c, off);
    if (c >= k) lo = mid; else hi = mid;
  }
  const unsigned threshKey = lo;

  float ss = 0.f;
#pragma unroll
  for (int i = 0; i < 8; ++i) {
    const unsigned* p = (const unsigned*)&d[i];
#pragma unroll
    for (int c4 = 0; c4 < 4; ++c4) {
#pragma unroll
      for (int hh = 0; hh < 2; ++hh) {
        const unsigned key = hh ? (p[c4] >> 16) : (p[c4] & 0xffffu);
        if (key >= threshKey) {
          const float v = __uint_as_float(key << 16);
          ss = fmaf(v, v, ss);
        }
      }
    }
  }
#pragma unroll
  for (int off = 32; off > 0; off >>= 1) ss += __shfl_xor(ss, off);
  const float inv = 1.f / fmaxf(sqrtf(ss), 1e-10f);

  const float vmaxf = __uint_as_float(kmax << 16);
  const float r127 = (kmax > 0) ? 127.f / vmaxf : 0.f;

  if (lane == 0) sA[row] = vmaxf * inv * (1.f / 127.f);

  uint2* o2 = (uint2*)(OUTQ + (size_t)row * 4096);
#pragma unroll
  for (int i = 0; i < 8; ++i) {
    const unsigned* p = (const unsigned*)&d[i];
    unsigned b[8];
#pragma unroll
    for (int c4 = 0; c4 < 4; ++c4) {
#pragma unroll
      for (int hh = 0; hh < 2; ++hh) {
        const unsigned key = hh ? (p[c4] >> 16) : (p[c4] & 0xffffu);
        unsigned q = 0;
        if (key >= threshKey && key > 0) {
          const float v = __uint_as_float(key << 16);
          q = (unsigned)__float2int_rn(v * r127) & 0xffu;
        }
        b[c4 * 2 + hh] = q;
      }
    }
    uint2 o;
    o.x = b[0] | (b[1] << 8) | (b[2] << 16) | (b[3] << 24);
    o.y = b[4] | (b[5] << 8) | (b[6] << 16) | (b[7] << 24);
    o2[(i << 6) + lane] = o;
  }
}

// ============================================================================
// Merged per-row quantization, one launch. wgl ranges:
//   [0,8192)      x      K=1024
//   [8192,12288)  W_down K=1024
//   [12288,13312) W_gate K=1024
//   [13312,17408) W_ca3  K=4096
//   [17408,18432) W_up   K=4096
// ============================================================================
__global__ void __launch_bounds__(256)
quant_all(const float* __restrict__ X,  const float* __restrict__ Wd,
          const float* __restrict__ Wg, const float* __restrict__ Wc,
          const float* __restrict__ Wu,
          uint8_t* __restrict__ xq,  uint8_t* __restrict__ wdq,
          uint8_t* __restrict__ wgq, uint8_t* __restrict__ wcq,
          uint8_t* __restrict__ wuq,
          float* __restrict__ sx,  float* __restrict__ swd,
          float* __restrict__ swg, float* __restrict__ swc,
          float* __restrict__ swu)
{
  const int wgl = ((int)blockIdx.x << 2) + (threadIdx.x >> 6);
  const int lane = threadIdx.x & 63;

  const float* W; uint8_t* q; float* s; int row; bool big;
  if      (wgl < 8192)  { W = X;  q = xq;  s = sx;  row = wgl;         big = false; }
  else if (wgl < 12288) { W = Wd; q = wdq; s = swd; row = wgl - 8192;  big = false; }
  else if (wgl < 13312) { W = Wg; q = wgq; s = swg; row = wgl - 12288; big = false; }
  else if (wgl < 17408) { W = Wc; q = wcq; s = swc; row = wgl - 13312; big = true; }
  else                  { W = Wu; q = wuq; s = swu; row = wgl - 17408; big = true; }

  if (!big) {
    const float4* src = (const float4*)(W + (size_t)row * 1024);
    float4 v[4];
    float am = 0.f;
#pragma unroll
    for (int i = 0; i < 4; ++i) {
      v[i] = src[(i << 6) + lane];
      am = fmaxf(am, fmaxf(fmaxf(fabsf(v[i].x), fabsf(v[i].y)),
                           fmaxf(fabsf(v[i].z), fabsf(v[i].w))));
    }
#pragma unroll
    for (int off = 32; off > 0; off >>= 1) am = fmaxf(am, __shfl_xor(am, off));
    const float rinv = (am > 0.f) ? 127.f / am : 0.f;
    uint4 o;
    unsigned* ob = (unsigned*)&o;
#pragma unroll
    for (int i = 0; i < 4; ++i) {
      const unsigned b0 = (unsigned)__float2int_rn(v[i].x * rinv) & 0xffu;
      const unsigned b1 = (unsigned)__float2int_rn(v[i].y * rinv) & 0xffu;
      const unsigned b2 = (unsigned)__float2int_rn(v[i].z * rinv) & 0xffu;
      const unsigned b3 = (unsigned)__float2int_rn(v[i].w * rinv) & 0xffu;
      ob[i] = b0 | (b1 << 8) | (b2 << 16) | (b3 << 24);
    }
    ((uint4*)(q + (size_t)row * 1024))[lane] = o;
    if (lane == 0) s[row] = am * (1.f / 127.f);
  } else {
    const float4* src = (const float4*)(W + (size_t)row * 4096);
    float4 v[16];
    float am = 0.f;
#pragma unroll
    for (int i = 0; i < 16; ++i) {
      v[i] = src[(i << 6) + lane];
      am = fmaxf(am, fmaxf(fmaxf(fabsf(v[i].x), fabsf(v[i].y)),
                           fmaxf(fabsf(v[i].z), fabsf(v[i].w))));
    }
#pragma unroll
    for (int off = 32; off > 0; off >>= 1) am = fmaxf(am, __shfl_xor(am, off));
    const float rinv = (am > 0.f) ? 127.f / am : 0.f;
    unsigned* qo = (unsigned*)(q + (size_t)row * 4096);
#pragma unroll
    for (int i = 0; i < 16; ++i) {
      const unsigned b0 = (unsigned)__float2int_rn(v[i].x * rinv) & 0xffu;
      const unsigned b1 = (unsigned)__float2int_rn(v[i].y * rinv) & 0xffu;
      const unsigned b2 = (unsigned)__float2int_rn(v[i].z * rinv) & 0xffu;
      const unsigned b3 = (unsigned)__float2int_rn(v[i].w * rinv) & 0xffu;
      qo[(i << 6) + lane] = b0 | (b1 << 8) | (b2 << 16) | (b3 << 24);
    }
    if (lane == 0) s[row] = am * (1.f / 127.f);
  }
}

__global__ void diag_kernel(float* out, float mb)
{
  if (threadIdx.x == 0 && blockIdx.x == 0) out[0] = -mb;
}

extern "C" void kernel_launch(void* const* d_in, const int* in_sizes, int n_in,
                              void* d_out, int out_size, void* d_ws, size_t ws_size,
                              hipStream_t stream)
{
  const float* x     = (const float*)d_in[0]; // (8192,1024)
  const float* Wdown = (const float*)d_in[1]; // (4096,1024)
  const float* Wup   = (const float*)d_in[2]; // (1024,4096)
  const float* Wgate = (const float*)d_in[3]; // (1024,1024)
  const float* bgate = (const float*)d_in[4]; // (1024,)
  const float* Wca3  = (const float*)d_in[5]; // (4096,4096)
  const int*   kptr  = (const int*)d_in[6];

  const size_t OFF_XQ   = 0;         //  8 MB i8 x
  const size_t OFF_WDQ  = 8388608;   //  4 MB i8 W_down
  const size_t OFF_WGQ  = 12582912;  //  1 MB i8 W_gate
  const size_t OFF_WCQ  = 13631488;  // 16 MB i8 W_ca3
  const size_t OFF_WUQ  = 30408704;  //  4 MB i8 W_up
  const size_t OFF_SX   = 34603008;  // 32 KB
  const size_t OFF_SWD  = 34635776;  // 16 KB
  const size_t OFF_SWG  = 34652160;  //  4 KB
  const size_t OFF_SWC  = 34656256;  // 16 KB
  const size_t OFF_SWU  = 34672640;  //  4 KB
  const size_t OFF_SA   = 34676736;  // 32 KB
  const size_t OFF_VSUM = 34709504;  //  4 KB pad
  const size_t OFF_SPQ  = 34713600;  // 32 MB i8 sparse/successor
  const size_t OFF_H    = 68268032;  // 64 MB bf16 h1/h2; pred (16 MB bf16) aliases
  const size_t NEED     = 135376896;

  if (ws_size < NEED) {
    diag_kernel<<<1, 64, 0, stream>>>((float*)d_out, (float)(ws_size >> 20));
    return;
  }

  char* ws = (char*)d_ws;
  uint8_t*        xq   = (uint8_t*)       (ws + OFF_XQ);
  uint8_t*        wdq  = (uint8_t*)       (ws + OFF_WDQ);
  uint8_t*        wgq  = (uint8_t*)       (ws + OFF_WGQ);
  uint8_t*        wcq  = (uint8_t*)       (ws + OFF_WCQ);
  uint8_t*        wuq  = (uint8_t*)       (ws + OFF_WUQ);
  float*          sx   = (float*)         (ws + OFF_SX);
  float*          swd  = (float*)         (ws + OFF_SWD);
  float*          swg  = (float*)         (ws + OFF_SWG);
  float*          swc  = (float*)         (ws + OFF_SWC);
  float*          swu  = (float*)         (ws + OFF_SWU);
  float*          sA   = (float*)         (ws + OFF_SA);
  float*          vsum = (float*)         (ws + OFF_VSUM);
  uint8_t*        spq  = (uint8_t*)       (ws + OFF_SPQ);
  __hip_bfloat16* h    = (__hip_bfloat16*)(ws + OFF_H);
  __hip_bfloat16* pred = (__hip_bfloat16*)(ws + OFF_H);   // aliases h (dead by then)

  hipMemsetAsync(vsum, 0, sizeof(float), stream);

  // quantize all inputs/weights to i8 with per-row scales (one launch)
  quant_all<<<4608, 256, 0, stream>>>(x, Wdown, Wgate, Wca3, Wup,
                                      xq, wdq, wgq, wcq, wuq,
                                      sx, swd, swg, swc, swu);

  // h1 = relu(sx*swd * (xq @ wdq^T)) -> bf16   [i8 8-phase 256^2, grid 512]
  gemm_i8_8ph<0><<<(MROWS >> 8) * (DN >> 8), 512, 131072, stream>>>(
      xq, wdq, h, MROWS, DN, DD, nullptr, sx, swd);
  // sparse = kwta(h1)/norm -> i8 + scale
  kwta_wave<0><<<MROWS / 4, 256, 0, stream>>>(h, spq, sA, nullptr, kptr);
  // h2 = relu(sA*swc * (spq @ wcq^T)) -> bf16, sum -> vsum   [i8 8-phase]
  gemm_i8_8ph<1><<<(MROWS >> 8) * (DN >> 8), 512, 131072, stream>>>(
      spq, wcq, h, MROWS, DN, DN, vsum, sA, swc);
  // successor = valid ? kwta(h2)/norm : sparse (i8 + scale, in-place)
  kwta_wave<1><<<MROWS / 4, 256, 0, stream>>>(h, spq, sA, vsum, kptr);
  // pred = (spq @ wuq^T) deq -> bf16   [i8 128^2 + swizzle, grid 512]
  gemm_i8_128<<<(MROWS >> 7) * (DD >> 7), 256, 0, stream>>>(
      spq, wuq, pred, MROWS, DD, DN, sA, swu);
  // out = x + sigmoid(deq(xq @ wgq^T) + bgate) * pred   [i8 128^2 + swizzle]
  gemm_gate_i8<<<(MROWS >> 7) * (DD >> 7), 256, 0, stream>>>(
      xq, wgq, (float*)d_out, MROWS, DD, DD, sx, swg, x, pred, bgate);
}

// Round 12
// 399.221 us; speedup vs baseline: 1.4011x; 1.0178x over previous
//
#include <hip/hip_runtime.h>
#include <hip/hip_bf16.h>
#include <stdint.h>

typedef float f32x4 __attribute__((ext_vector_type(4)));
typedef int i32x4 __attribute__((ext_vector_type(4)));

#define MROWS 8192
#define DD 1024
#define DN 4096

__device__ __forceinline__ void load_lds16(const void* g, void* l) {
  __builtin_amdgcn_global_load_lds((const __attribute__((address_space(1))) void*)g,
                                   (__attribute__((address_space(3))) void*)l, 16, 0, 0);
}

// ============================================================================
// 256x256 8-phase INT8 GEMM (verified schedule; pipelined frag reads,
// vmcnt(6) odd phases). K bytes, K-tile=128B, NT=K>>7.
// SUPERTILE bid mapping (hardcoded for grid 512, M=8192, N=4096): XCDs tiled
// 4x2 over the 32x16 panel grid; each XCD owns an 8x8 panel chunk ->
// per-XCD unique working set 16 MB (was 20 MB with row-major swizzle).
// EPI 0: h = relu(deq) -> bf16.   EPI 1: + block sum -> atomicAdd(vsum).
// ============================================================================
template<int EPI>
__global__ void __launch_bounds__(512, 1)
gemm_i8_8ph(const uint8_t* __restrict__ A, const uint8_t* __restrict__ B,
            __hip_bfloat16* __restrict__ Cb, int M, int N, int K,
            float* __restrict__ vsum,
            const float* __restrict__ sA, const float* __restrict__ sB)
{
  extern __shared__ __align__(16) char smem[];
  const int tid  = threadIdx.x;
  const int lane = tid & 63;
  const int wave = tid >> 6;
  const int wm = wave >> 2;
  const int wn = wave & 3;

  // supertile: xcd in 4x2 grid, 8x8 panels per XCD (bijective for 512 blocks)
  const int xcd = (int)blockIdx.x & 7;
  const int loc = (int)blockIdx.x >> 3;   // 0..63
  const int bm = ((((xcd >> 1) << 3) + (loc >> 3)) << 8);
  const int bn = ((((xcd & 1) << 3) + (loc & 7)) << 8);

  const int NT = K >> 7;

  i32x4 acc[8][4];
  const i32x4 izero = {0, 0, 0, 0};
#pragma unroll
  for (int i = 0; i < 8; ++i)
#pragma unroll
    for (int j = 0; j < 4; ++j)
      acc[i][j] = izero;

  const int csb = (((tid & 3) ^ ((tid >> 3) & 3)) << 4);
  const uint8_t* Ag = A + (size_t)(bm + (tid >> 2)) * K + csb;
  const uint8_t* Bg = B + (size_t)(bn + (tid >> 2)) * K + csb;

  const int rl = lane & 15;
  const int kc = lane >> 4;
  const int chunk_off = ((kc ^ ((rl >> 1) & 3)) << 4);
  const int aoff = ((wm << 7) + rl) * 64 + chunk_off;
  const int boff = ((wn << 6) + rl) * 64 + chunk_off;

#define STAGE_A8(S, KH) do { \
    const int kt_ = (((S) & (NT - 1)) << 7) + ((KH) << 6); \
    char* dst_ = smem + (((((S) & 1) << 1) | (KH)) << 14) + (tid << 4); \
    load_lds16(Ag + kt_, dst_); \
    load_lds16(Ag + (size_t)128 * K + kt_, dst_ + 8192); \
  } while (0)

#define STAGE_B8(S, KH) do { \
    const int kt_ = (((S) & (NT - 1)) << 7) + ((KH) << 6); \
    char* dst_ = smem + 65536 + (((((S) & 1) << 1) | (KH)) << 14) + (tid << 4); \
    load_lds16(Bg + kt_, dst_); \
    load_lds16(Bg + (size_t)128 * K + kt_, dst_ + 8192); \
  } while (0)

  i32x4 afS[2][4];
  i32x4 b0, b1, b2, b3;

#define MFMA_ROW8(MI, AF) \
    acc[MI][0] = __builtin_amdgcn_mfma_i32_16x16x64_i8(AF, b0, acc[MI][0], 0, 0, 0); \
    acc[MI][1] = __builtin_amdgcn_mfma_i32_16x16x64_i8(AF, b1, acc[MI][1], 0, 0, 0); \
    acc[MI][2] = __builtin_amdgcn_mfma_i32_16x16x64_i8(AF, b2, acc[MI][2], 0, 0, 0); \
    acc[MI][3] = __builtin_amdgcn_mfma_i32_16x16x64_i8(AF, b3, acc[MI][3], 0, 0, 0);

#define PH8(PN, KHN, MHN, ASETN, ACUR, MHC, DOBP, BP, BKH, STG, VM) do { \
    { const char* ab_ = smem + ((((PN) << 1) | (KHN)) << 14) + aoff + (MHN) * 4096; \
      afS[ASETN][0] = *(const i32x4*)(ab_); \
      afS[ASETN][1] = *(const i32x4*)(ab_ + 1024); \
      afS[ASETN][2] = *(const i32x4*)(ab_ + 2048); \
      afS[ASETN][3] = *(const i32x4*)(ab_ + 3072); } \
    STG; \
    if (VM) { asm volatile("s_waitcnt vmcnt(6)" ::: "memory"); } \
    asm volatile("s_barrier" ::: "memory"); \
    __builtin_amdgcn_sched_barrier(0); \
    __builtin_amdgcn_s_setprio(1); \
    MFMA_ROW8((MHC) * 4 + 0, afS[ACUR][0]) \
    MFMA_ROW8((MHC) * 4 + 1, afS[ACUR][1]) \
    MFMA_ROW8((MHC) * 4 + 2, afS[ACUR][2]) \
    MFMA_ROW8((MHC) * 4 + 3, afS[ACUR][3]) \
    __builtin_amdgcn_s_setprio(0); \
    if (DOBP) { \
      const char* bb_ = smem + 65536 + ((((BP) << 1) | (BKH)) << 14) + boff; \
      b0 = *(const i32x4*)(bb_); b1 = *(const i32x4*)(bb_ + 1024); \
      b2 = *(const i32x4*)(bb_ + 2048); b3 = *(const i32x4*)(bb_ + 3072); } \
    asm volatile("s_barrier" ::: "memory"); \
  } while (0)

  STAGE_A8(0, 0); STAGE_B8(0, 0);
  STAGE_A8(0, 1); STAGE_B8(0, 1);
  STAGE_A8(1, 0); STAGE_B8(1, 0);
  asm volatile("s_waitcnt vmcnt(4)" ::: "memory");
  asm volatile("s_barrier" ::: "memory");
  {
    const char* ab_ = smem + aoff;
    afS[1][0] = *(const i32x4*)(ab_);
    afS[1][1] = *(const i32x4*)(ab_ + 1024);
    afS[1][2] = *(const i32x4*)(ab_ + 2048);
    afS[1][3] = *(const i32x4*)(ab_ + 3072);
    const char* bb_ = smem + 65536 + boff;
    b0 = *(const i32x4*)(bb_); b1 = *(const i32x4*)(bb_ + 1024);
    b2 = *(const i32x4*)(bb_ + 2048); b3 = *(const i32x4*)(bb_ + 3072);
  }

#pragma unroll 1
  for (int t = 0; t < NT; t += 2) {
    PH8(0, 0, 1, 0, 1, 0, 0, 0, 0, STAGE_A8(t + 1, 1), 1);
    PH8(0, 1, 0, 1, 0, 1, 1, 0, 1, STAGE_B8(t + 1, 1), 0);
    PH8(0, 1, 1, 0, 1, 0, 0, 0, 0, STAGE_A8(t + 2, 0), 1);
    PH8(1, 0, 0, 1, 0, 1, 1, 1, 0, STAGE_B8(t + 2, 0), 0);
    PH8(1, 0, 1, 0, 1, 0, 0, 0, 0, STAGE_A8(t + 2, 1), 1);
    PH8(1, 1, 0, 1, 0, 1, 1, 1, 1, STAGE_B8(t + 2, 1), 0);
    PH8(1, 1, 1, 0, 1, 0, 0, 0, 0, STAGE_A8(t + 3, 0), 1);
    PH8(0, 0, 0, 1, 0, 1, 1, 0, 0, STAGE_B8(t + 3, 0), 0);
  }

  const int r0 = bm + (wm << 7) + (kc << 2);
  const int c0 = bn + (wn << 6) + rl;
  float lsum = 0.f;
#pragma unroll
  for (int mi = 0; mi < 8; ++mi) {
#pragma unroll
    for (int nf = 0; nf < 4; ++nf) {
#pragma unroll
      for (int q = 0; q < 4; ++q) {
        const int r = r0 + (mi << 4) + q;
        const int c = c0 + (nf << 4);
        float v = (float)acc[mi][nf][q] * sA[r] * sB[c];
        v = fmaxf(v, 0.f);
        Cb[(size_t)r * N + c] = __float2bfloat16(v);
        if constexpr (EPI == 1) lsum += v;
      }
    }
  }
  if constexpr (EPI == 1) {
#pragma unroll
    for (int off = 32; off > 0; off >>= 1)
      lsum += __shfl_down(lsum, off);
    if (lane == 0) atomicAdd(vsum, lsum);
  }

#undef STAGE_A8
#undef STAGE_B8
#undef MFMA_ROW8
#undef PH8
}

// ============================================================================
// 128x128 2-barrier INT8 GEMM (verified) + XCD swizzle — pred:
// pred = (spq @ wuq^T) * sA[r] * sB[c] -> bf16 (no relu).
// ============================================================================
__global__ void __launch_bounds__(256)
gemm_i8_128(const uint8_t* __restrict__ A, const uint8_t* __restrict__ B,
            __hip_bfloat16* __restrict__ Cb, int M, int N, int K,
            const float* __restrict__ sA, const float* __restrict__ sB)
{
  __shared__ __align__(16) char smem[32768];
  const int tid  = threadIdx.x;
  const int lane = tid & 63;
  const int wave = tid >> 6;

  const int nwg = gridDim.x;
  const int bid = ((int)blockIdx.x % 8) * (nwg >> 3) + ((int)blockIdx.x >> 3);

  const int nbn = N >> 7;
  const int bm = (bid / nbn) << 7;
  const int bn = (bid % nbn) << 7;

  const int wm = (wave >> 1) << 6;
  const int wn = (wave & 1) << 6;

  i32x4 acc[4][4];
  const i32x4 izero = {0, 0, 0, 0};
#pragma unroll
  for (int i = 0; i < 4; ++i)
#pragma unroll
    for (int j = 0; j < 4; ++j)
      acc[i][j] = izero;

  const int srow = tid >> 3;
  const int schk = (tid & 7) ^ (srow & 7);
  const uint8_t* Ag = A + (size_t)(bm + srow) * K + (schk << 4);
  const uint8_t* Bg = B + (size_t)(bn + srow) * K + (schk << 4);
  char* ldsA = smem + (wave << 10);
  char* ldsB = smem + 16384 + (wave << 10);

  const int aoff0 = (wm + (lane & 15)) << 7;
  const int boff0 = 16384 + ((wn + (lane & 15)) << 7);
  const int kc = lane >> 4;
  const int sw = lane & 7;

  for (int k0 = 0; k0 < K; k0 += 128) {
#pragma unroll
    for (int i = 0; i < 4; ++i)
      load_lds16(Ag + (size_t)(i << 5) * K + k0, ldsA + (i << 12));
#pragma unroll
    for (int i = 0; i < 4; ++i)
      load_lds16(Bg + (size_t)(i << 5) * K + k0, ldsB + (i << 12));
    __syncthreads();
#pragma unroll
    for (int ks = 0; ks < 2; ++ks) {
      const int cb = ((kc + (ks << 2)) ^ sw) << 4;
      i32x4 af[4], bfr[4];
#pragma unroll
      for (int i = 0; i < 4; ++i)
        af[i] = *reinterpret_cast<const i32x4*>(smem + aoff0 + (i << 11) + cb);
#pragma unroll
      for (int j = 0; j < 4; ++j)
        bfr[j] = *reinterpret_cast<const i32x4*>(smem + boff0 + (j << 11) + cb);
#pragma unroll
      for (int i = 0; i < 4; ++i)
#pragma unroll
        for (int j = 0; j < 4; ++j)
          acc[i][j] = __builtin_amdgcn_mfma_i32_16x16x64_i8(af[i], bfr[j], acc[i][j], 0, 0, 0);
    }
    __syncthreads();
  }

  const int r0 = bm + wm + ((lane >> 4) << 2);
  const int c0 = bn + wn + (lane & 15);
#pragma unroll
  for (int i = 0; i < 4; ++i)
#pragma unroll
    for (int j = 0; j < 4; ++j)
#pragma unroll
      for (int q = 0; q < 4; ++q) {
        const int r = r0 + (i << 4) + q;
        const int c = c0 + (j << 4);
        Cb[(size_t)r * N + c] =
            __float2bfloat16((float)acc[i][j][q] * sA[r] * sB[c]);
      }
}

// ============================================================================
// 128x128 2-barrier INT8 gate GEMM + fused final epilogue:
// out = x + sigmoid(deq(xq@wgq^T) + bgate) * pred(bf16)   (f32 out)
// ============================================================================
__global__ void __launch_bounds__(256)
gemm_gate_i8(const uint8_t* __restrict__ A, const uint8_t* __restrict__ B,
             float* __restrict__ Cf, int M, int N, int K,
             const float* __restrict__ sA, const float* __restrict__ sB,
             const float* __restrict__ Xf, const __hip_bfloat16* __restrict__ PredBf,
             const float* __restrict__ Bgate)
{
  __shared__ __align__(16) char smem[32768];
  const int tid  = threadIdx.x;
  const int lane = tid & 63;
  const int wave = tid >> 6;

  const int nwg = gridDim.x;
  const int bid = ((int)blockIdx.x % 8) * (nwg >> 3) + ((int)blockIdx.x >> 3);

  const int nbn = N >> 7;
  const int bm = (bid / nbn) << 7;
  const int bn = (bid % nbn) << 7;

  const int wm = (wave >> 1) << 6;
  const int wn = (wave & 1) << 6;

  i32x4 acc[4][4];
  const i32x4 izero = {0, 0, 0, 0};
#pragma unroll
  for (int i = 0; i < 4; ++i)
#pragma unroll
    for (int j = 0; j < 4; ++j) acc[i][j] = izero;

  const int srow = tid >> 3;
  const int schk = (tid & 7) ^ (srow & 7);
  const uint8_t* Ag = A + (size_t)(bm + srow) * K + (schk << 4);
  const uint8_t* Bg = B + (size_t)(bn + srow) * K + (schk << 4);
  char* ldsA = smem + (wave << 10);
  char* ldsB = smem + 16384 + (wave << 10);

  const int aoff0 = (wm + (lane & 15)) << 7;
  const int boff0 = 16384 + ((wn + (lane & 15)) << 7);
  const int kc = lane >> 4;
  const int sw = lane & 7;

  for (int k0 = 0; k0 < K; k0 += 128) {
#pragma unroll
    for (int i = 0; i < 4; ++i)
      load_lds16(Ag + (size_t)(i << 5) * K + k0, ldsA + (i << 12));
#pragma unroll
    for (int i = 0; i < 4; ++i)
      load_lds16(Bg + (size_t)(i << 5) * K + k0, ldsB + (i << 12));
    __syncthreads();
#pragma unroll
    for (int ks = 0; ks < 2; ++ks) {
      const int cb = ((kc + (ks << 2)) ^ sw) << 4;
      i32x4 af[4], bfr[4];
#pragma unroll
      for (int i = 0; i < 4; ++i)
        af[i] = *reinterpret_cast<const i32x4*>(smem + aoff0 + (i << 11) + cb);
#pragma unroll
      for (int j = 0; j < 4; ++j)
        bfr[j] = *reinterpret_cast<const i32x4*>(smem + boff0 + (j << 11) + cb);
#pragma unroll
      for (int i = 0; i < 4; ++i)
#pragma unroll
        for (int j = 0; j < 4; ++j)
          acc[i][j] = __builtin_amdgcn_mfma_i32_16x16x64_i8(af[i], bfr[j], acc[i][j], 0, 0, 0);
    }
    __syncthreads();
  }

  const int r0 = bm + wm + ((lane >> 4) << 2);
  const int c0 = bn + wn + (lane & 15);
#pragma unroll
  for (int i = 0; i < 4; ++i)
#pragma unroll
    for (int j = 0; j < 4; ++j)
#pragma unroll
      for (int q = 0; q < 4; ++q) {
        const int r = r0 + (i << 4) + q;
        const int c = c0 + (j << 4);
        const size_t idx = (size_t)r * N + c;
        const float vg = (float)acc[i][j][q] * sA[r] * sB[c] + Bgate[c];
        const float g = 1.f / (1.f + __expf(-vg));
        Cf[idx] = Xf[idx] + g * __bfloat162float(PredBf[idx]);
      }
}

// ============================================================================
// kwta, wave-per-row (verified). Exact threshold via 16-step binary search on
// u16 bf16 keys (nonneg). Emits INT8 normalized row + scale.
// MODE 0: always write.  MODE 1: only when *vsumPtr >= EPS (else keep old).
// ============================================================================
template<int MODE>
__global__ void __launch_bounds__(256)
kwta_wave(const __hip_bfloat16* __restrict__ H, uint8_t* __restrict__ OUTQ,
          float* __restrict__ sA, const float* __restrict__ vsumPtr,
          const int* __restrict__ kptr)
{
  const int tid  = threadIdx.x;
  const int lane = tid & 63;
  const int w    = tid >> 6;
  const int row  = ((int)blockIdx.x << 2) + w;

  if constexpr (MODE == 1) {
    if (!(*vsumPtr >= 1e-10f)) return;
  }

  const uint4* h8 = (const uint4*)(H + (size_t)row * 4096);
  uint4 d[8];
#pragma unroll
  for (int i = 0; i < 8; ++i) d[i] = h8[(i << 6) + lane];

  const unsigned k = (unsigned)(*kptr);

  unsigned kmax = 0;
#pragma unroll
  for (int i = 0; i < 8; ++i) {
    const unsigned* p = (const unsigned*)&d[i];
#pragma unroll
    for (int c4 = 0; c4 < 4; ++c4) {
      kmax = max(kmax, p[c4] & 0xffffu);
      kmax = max(kmax, p[c4] >> 16);
    }
  }
#pragma unroll
  for (int off = 32; off > 0; off >>= 1) kmax = max(kmax, __shfl_xor(kmax, off));

  unsigned lo = 0, hi = 65536;
#pragma unroll 1
  for (int it = 0; it < 16; ++it) {
    const unsigned mid = (lo + hi) >> 1;
    unsigned c = 0;
#pragma unroll
    for (int i = 0; i < 8; ++i) {
      const unsigned* p = (const unsigned*)&d[i];
#pragma unroll
      for (int c4 = 0; c4 < 4; ++c4) {
        c += ((p[c4] & 0xffffu) >= mid) ? 1u : 0u;
        c += ((p[c4] >> 16) >= mid) ? 1u : 0u;
      }
    }
#pragma unroll
    for (int off = 32; off > 0; off >>= 1) c += __shfl_xor(c, off);
    if (c >= k) lo = mid; else hi = mid;
  }
  const unsigned threshKey = lo;

  float ss = 0.f;
#pragma unroll
  for (int i = 0; i < 8; ++i) {
    const unsigned* p = (const unsigned*)&d[i];
#pragma unroll
    for (int c4 = 0; c4 < 4; ++c4) {
#pragma unroll
      for (int hh = 0; hh < 2; ++hh) {
        const unsigned key = hh ? (p[c4] >> 16) : (p[c4] & 0xffffu);
        if (key >= threshKey) {
          const float v = __uint_as_float(key << 16);
          ss = fmaf(v, v, ss);
        }
      }
    }
  }
#pragma unroll
  for (int off = 32; off > 0; off >>= 1) ss += __shfl_xor(ss, off);
  const float inv = 1.f / fmaxf(sqrtf(ss), 1e-10f);

  const float vmaxf = __uint_as_float(kmax << 16);
  const float r127 = (kmax > 0) ? 127.f / vmaxf : 0.f;

  if (lane == 0) sA[row] = vmaxf * inv * (1.f / 127.f);

  uint2* o2 = (uint2*)(OUTQ + (size_t)row * 4096);
#pragma unroll
  for (int i = 0; i < 8; ++i) {
    const unsigned* p = (const unsigned*)&d[i];
    unsigned b[8];
#pragma unroll
    for (int c4 = 0; c4 < 4; ++c4) {
#pragma unroll
      for (int hh = 0; hh < 2; ++hh) {
        const unsigned key = hh ? (p[c4] >> 16) : (p[c4] & 0xffffu);
        unsigned q = 0;
        if (key >= threshKey && key > 0) {
          const float v = __uint_as_float(key << 16);
          q = (unsigned)__float2int_rn(v * r127) & 0xffu;
        }
        b[c4 * 2 + hh] = q;
      }
    }
    uint2 o;
    o.x = b[0] | (b[1] << 8) | (b[2] << 16) | (b[3] << 24);
    o.y = b[4] | (b[5] << 8) | (b[6] << 16) | (b[7] << 24);
    o2[(i << 6) + lane] = o;
  }
}

// ============================================================================
// Merged per-row quantization, one launch; also zero-inits vsum (block 0).
// ============================================================================
__global__ void __launch_bounds__(256)
quant_all(const float* __restrict__ X,  const float* __restrict__ Wd,
          const float* __restrict__ Wg, const float* __restrict__ Wc,
          const float* __restrict__ Wu,
          uint8_t* __restrict__ xq,  uint8_t* __restrict__ wdq,
          uint8_t* __restrict__ wgq, uint8_t* __restrict__ wcq,
          uint8_t* __restrict__ wuq,
          float* __restrict__ sx,  float* __restrict__ swd,
          float* __restrict__ swg, float* __restrict__ swc,
          float* __restrict__ swu, float* __restrict__ vsum)
{
  if (blockIdx.x == 0 && threadIdx.x == 0) *vsum = 0.f;

  const int wgl = ((int)blockIdx.x << 2) + (threadIdx.x >> 6);
  const int lane = threadIdx.x & 63;

  const float* W; uint8_t* q; float* s; int row; bool big;
  if      (wgl < 8192)  { W = X;  q = xq;  s = sx;  row = wgl;         big = false; }
  else if (wgl < 12288) { W = Wd; q = wdq; s = swd; row = wgl - 8192;  big = false; }
  else if (wgl < 13312) { W = Wg; q = wgq; s = swg; row = wgl - 12288; big = false; }
  else if (wgl < 17408) { W = Wc; q = wcq; s = swc; row = wgl - 13312; big = true; }
  else                  { W = Wu; q = wuq; s = swu; row = wgl - 17408; big = true; }

  if (!big) {
    const float4* src = (const float4*)(W + (size_t)row * 1024);
    float4 v[4];
    float am = 0.f;
#pragma unroll
    for (int i = 0; i < 4; ++i) {
      v[i] = src[(i << 6) + lane];
      am = fmaxf(am, fmaxf(fmaxf(fabsf(v[i].x), fabsf(v[i].y)),
                           fmaxf(fabsf(v[i].z), fabsf(v[i].w))));
    }
#pragma unroll
    for (int off = 32; off > 0; off >>= 1) am = fmaxf(am, __shfl_xor(am, off));
    const float rinv = (am > 0.f) ? 127.f / am : 0.f;
    uint4 o;
    unsigned* ob = (unsigned*)&o;
#pragma unroll
    for (int i = 0; i < 4; ++i) {
      const unsigned b0 = (unsigned)__float2int_rn(v[i].x * rinv) & 0xffu;
      const unsigned b1 = (unsigned)__float2int_rn(v[i].y * rinv) & 0xffu;
      const unsigned b2 = (unsigned)__float2int_rn(v[i].z * rinv) & 0xffu;
      const unsigned b3 = (unsigned)__float2int_rn(v[i].w * rinv) & 0xffu;
      ob[i] = b0 | (b1 << 8) | (b2 << 16) | (b3 << 24);
    }
    ((uint4*)(q + (size_t)row * 1024))[lane] = o;
    if (lane == 0) s[row] = am * (1.f / 127.f);
  } else {
    const float4* src = (const float4*)(W + (size_t)row * 4096);
    float4 v[16];
    float am = 0.f;
#pragma unroll
    for (int i = 0; i < 16; ++i) {
      v[i] = src[(i << 6) + lane];
      am = fmaxf(am, fmaxf(fmaxf(fabsf(v[i].x), fabsf(v[i].y)),
                           fmaxf(fabsf(v[i].z), fabsf(v[i].w))));
    }
#pragma unroll
    for (int off = 32; off > 0; off >>= 1) am = fmaxf(am, __shfl_xor(am, off));
    const float rinv = (am > 0.f) ? 127.f / am : 0.f;
    unsigned* qo = (unsigned*)(q + (size_t)row * 4096);
#pragma unroll
    for (int i = 0; i < 16; ++i) {
      const unsigned b0 = (unsigned)__float2int_rn(v[i].x * rinv) & 0xffu;
      const unsigned b1 = (unsigned)__float2int_rn(v[i].y * rinv) & 0xffu;
      const unsigned b2 = (unsigned)__float2int_rn(v[i].z * rinv) & 0xffu;
      const unsigned b3 = (unsigned)__float2int_rn(v[i].w * rinv) & 0xffu;
      qo[(i << 6) + lane] = b0 | (b1 << 8) | (b2 << 16) | (b3 << 24);
    }
    if (lane == 0) s[row] = am * (1.f / 127.f);
  }
}

__global__ void diag_kernel(float* out, float mb)
{
  if (threadIdx.x == 0 && blockIdx.x == 0) out[0] = -mb;
}

extern "C" void kernel_launch(void* const* d_in, const int* in_sizes, int n_in,
                              void* d_out, int out_size, void* d_ws, size_t ws_size,
                              hipStream_t stream)
{
  const float* x     = (const float*)d_in[0]; // (8192,1024)
  const float* Wdown = (const float*)d_in[1]; // (4096,1024)
  const float* Wup   = (const float*)d_in[2]; // (1024,4096)
  const float* Wgate = (const float*)d_in[3]; // (1024,1024)
  const float* bgate = (const float*)d_in[4]; // (1024,)
  const float* Wca3  = (const float*)d_in[5]; // (4096,4096)
  const int*   kptr  = (const int*)d_in[6];

  const size_t OFF_XQ   = 0;         //  8 MB i8 x
  const size_t OFF_WDQ  = 8388608;   //  4 MB i8 W_down
  const size_t OFF_WGQ  = 12582912;  //  1 MB i8 W_gate
  const size_t OFF_WCQ  = 13631488;  // 16 MB i8 W_ca3
  const size_t OFF_WUQ  = 30408704;  //  4 MB i8 W_up
  const size_t OFF_SX   = 34603008;  // 32 KB
  const size_t OFF_SWD  = 34635776;  // 16 KB
  const size_t OFF_SWG  = 34652160;  //  4 KB
  const size_t OFF_SWC  = 34656256;  // 16 KB
  const size_t OFF_SWU  = 34672640;  //  4 KB
  const size_t OFF_SA   = 34676736;  // 32 KB
  const size_t OFF_VSUM = 34709504;  //  4 KB pad
  const size_t OFF_SPQ  = 34713600;  // 32 MB i8 sparse/successor
  const size_t OFF_H    = 68268032;  // 64 MB bf16 h1/h2; pred (16 MB bf16) aliases
  const size_t NEED     = 135376896;

  if (ws_size < NEED) {
    diag_kernel<<<1, 64, 0, stream>>>((float*)d_out, (float)(ws_size >> 20));
    return;
  }

  char* ws = (char*)d_ws;
  uint8_t*        xq   = (uint8_t*)       (ws + OFF_XQ);
  uint8_t*        wdq  = (uint8_t*)       (ws + OFF_WDQ);
  uint8_t*        wgq  = (uint8_t*)       (ws + OFF_WGQ);
  uint8_t*        wcq  = (uint8_t*)       (ws + OFF_WCQ);
  uint8_t*        wuq  = (uint8_t*)       (ws + OFF_WUQ);
  float*          sx   = (float*)         (ws + OFF_SX);
  float*          swd  = (float*)         (ws + OFF_SWD);
  float*          swg  = (float*)         (ws + OFF_SWG);
  float*          swc  = (float*)         (ws + OFF_SWC);
  float*          swu  = (float*)         (ws + OFF_SWU);
  float*          sA   = (float*)         (ws + OFF_SA);
  float*          vsum = (float*)         (ws + OFF_VSUM);
  uint8_t*        spq  = (uint8_t*)       (ws + OFF_SPQ);
  __hip_bfloat16* h    = (__hip_bfloat16*)(ws + OFF_H);
  __hip_bfloat16* pred = (__hip_bfloat16*)(ws + OFF_H);   // aliases h (dead by then)

  // quantize all inputs/weights to i8 with per-row scales; zero vsum
  quant_all<<<4608, 256, 0, stream>>>(x, Wdown, Wgate, Wca3, Wup,
                                      xq, wdq, wgq, wcq, wuq,
                                      sx, swd, swg, swc, swu, vsum);

  // h1 = relu(sx*swd * (xq @ wdq^T)) -> bf16   [i8 8-phase 256^2, supertile]
  gemm_i8_8ph<0><<<(MROWS >> 8) * (DN >> 8), 512, 131072, stream>>>(
      xq, wdq, h, MROWS, DN, DD, nullptr, sx, swd);
  // sparse = kwta(h1)/norm -> i8 + scale
  kwta_wave<0><<<MROWS / 4, 256, 0, stream>>>(h, spq, sA, nullptr, kptr);
  // h2 = relu(sA*swc * (spq @ wcq^T)) -> bf16, sum -> vsum   [i8 8-phase]
  gemm_i8_8ph<1><<<(MROWS >> 8) * (DN >> 8), 512, 131072, stream>>>(
      spq, wcq, h, MROWS, DN, DN, vsum, sA, swc);
  // successor = valid ? kwta(h2)/norm : sparse (i8 + scale, in-place)
  kwta_wave<1><<<MROWS / 4, 256, 0, stream>>>(h, spq, sA, vsum, kptr);
  // pred = (spq @ wuq^T) deq -> bf16   [i8 128^2 + swizzle, grid 512]
  gemm_i8_128<<<(MROWS >> 7) * (DD >> 7), 256, 0, stream>>>(
      spq, wuq, pred, MROWS, DD, DN, sA, swu);
  // out = x + sigmoid(deq(xq @ wgq^T) + bgate) * pred   [i8 128^2 + swizzle]
  gemm_gate_i8<<<(MROWS >> 7) * (DD >> 7), 256, 0, stream>>>(
      xq, wgq, (float*)d_out, MROWS, DD, DD, sx, swg, x, pred, bgate);
}

// Round 15
// 396.829 us; speedup vs baseline: 1.4095x; 1.0060x over previous
//
#include <hip/hip_runtime.h>
#include <hip/hip_bf16.h>
#include <stdint.h>

typedef float f32x4 __attribute__((ext_vector_type(4)));
typedef int i32x4 __attribute__((ext_vector_type(4)));

#define MROWS 8192
#define DD 1024
#define DN 4096

__device__ __forceinline__ void load_lds16(const void* g, void* l) {
  __builtin_amdgcn_global_load_lds((const __attribute__((address_space(1))) void*)g,
                                   (__attribute__((address_space(3))) void*)l, 16, 0, 0);
}

// ============================================================================
// 256x256 8-phase INT8 GEMM (verified schedule; pipelined frag reads,
// vmcnt(6) odd phases). K bytes, K-tile=128B, NT=K>>7.
// SUPERTILE bid mapping (hardcoded for grid 512, M=8192, N=4096): XCDs tiled
// 4x2 over the 32x16 panel grid; each XCD owns an 8x8 panel chunk ->
// per-XCD unique working set 16 MB (was 20 MB with row-major swizzle).
// EPI 0: h = relu(deq) -> bf16.   EPI 1: + block sum -> atomicAdd(vsum).
// ============================================================================
template<int EPI>
__global__ void __launch_bounds__(512, 1)
gemm_i8_8ph(const uint8_t* __restrict__ A, const uint8_t* __restrict__ B,
            __hip_bfloat16* __restrict__ Cb, int M, int N, int K,
            float* __restrict__ vsum,
            const float* __restrict__ sA, const float* __restrict__ sB)
{
  extern __shared__ __align__(16) char smem[];
  const int tid  = threadIdx.x;
  const int lane = tid & 63;
  const int wave = tid >> 6;
  const int wm = wave >> 2;
  const int wn = wave & 3;

  // supertile: xcd in 4x2 grid, 8x8 panels per XCD (bijective for 512 blocks)
  const int xcd = (int)blockIdx.x & 7;
  const int loc = (int)blockIdx.x >> 3;   // 0..63
  const int bm = ((((xcd >> 1) << 3) + (loc >> 3)) << 8);
  const int bn = ((((xcd & 1) << 3) + (loc & 7)) << 8);

  const int NT = K >> 7;

  i32x4 acc[8][4];
  const i32x4 izero = {0, 0, 0, 0};
#pragma unroll
  for (int i = 0; i < 8; ++i)
#pragma unroll
    for (int j = 0; j < 4; ++j)
      acc[i][j] = izero;

  const int csb = (((tid & 3) ^ ((tid >> 3) & 3)) << 4);
  const uint8_t* Ag = A + (size_t)(bm + (tid >> 2)) * K + csb;
  const uint8_t* Bg = B + (size_t)(bn + (tid >> 2)) * K + csb;

  const int rl = lane & 15;
  const int kc = lane >> 4;
  const int chunk_off = ((kc ^ ((rl >> 1) & 3)) << 4);
  const int aoff = ((wm << 7) + rl) * 64 + chunk_off;
  const int boff = ((wn << 6) + rl) * 64 + chunk_off;

#define STAGE_A8(S, KH) do { \
    const int kt_ = (((S) & (NT - 1)) << 7) + ((KH) << 6); \
    char* dst_ = smem + (((((S) & 1) << 1) | (KH)) << 14) + (tid << 4); \
    load_lds16(Ag + kt_, dst_); \
    load_lds16(Ag + (size_t)128 * K + kt_, dst_ + 8192); \
  } while (0)

#define STAGE_B8(S, KH) do { \
    const int kt_ = (((S) & (NT - 1)) << 7) + ((KH) << 6); \
    char* dst_ = smem + 65536 + (((((S) & 1) << 1) | (KH)) << 14) + (tid << 4); \
    load_lds16(Bg + kt_, dst_); \
    load_lds16(Bg + (size_t)128 * K + kt_, dst_ + 8192); \
  } while (0)

  i32x4 afS[2][4];
  i32x4 b0, b1, b2, b3;

#define MFMA_ROW8(MI, AF) \
    acc[MI][0] = __builtin_amdgcn_mfma_i32_16x16x64_i8(AF, b0, acc[MI][0], 0, 0, 0); \
    acc[MI][1] = __builtin_amdgcn_mfma_i32_16x16x64_i8(AF, b1, acc[MI][1], 0, 0, 0); \
    acc[MI][2] = __builtin_amdgcn_mfma_i32_16x16x64_i8(AF, b2, acc[MI][2], 0, 0, 0); \
    acc[MI][3] = __builtin_amdgcn_mfma_i32_16x16x64_i8(AF, b3, acc[MI][3], 0, 0, 0);

#define PH8(PN, KHN, MHN, ASETN, ACUR, MHC, DOBP, BP, BKH, STG, VM) do { \
    { const char* ab_ = smem + ((((PN) << 1) | (KHN)) << 14) + aoff + (MHN) * 4096; \
      afS[ASETN][0] = *(const i32x4*)(ab_); \
      afS[ASETN][1] = *(const i32x4*)(ab_ + 1024); \
      afS[ASETN][2] = *(const i32x4*)(ab_ + 2048); \
      afS[ASETN][3] = *(const i32x4*)(ab_ + 3072); } \
    STG; \
    if (VM) { asm volatile("s_waitcnt vmcnt(6)" ::: "memory"); } \
    asm volatile("s_barrier" ::: "memory"); \
    __builtin_amdgcn_sched_barrier(0); \
    __builtin_amdgcn_s_setprio(1); \
    MFMA_ROW8((MHC) * 4 + 0, afS[ACUR][0]) \
    MFMA_ROW8((MHC) * 4 + 1, afS[ACUR][1]) \
    MFMA_ROW8((MHC) * 4 + 2, afS[ACUR][2]) \
    MFMA_ROW8((MHC) * 4 + 3, afS[ACUR][3]) \
    __builtin_amdgcn_s_setprio(0); \
    if (DOBP) { \
      const char* bb_ = smem + 65536 + ((((BP) << 1) | (BKH)) << 14) + boff; \
      b0 = *(const i32x4*)(bb_); b1 = *(const i32x4*)(bb_ + 1024); \
      b2 = *(const i32x4*)(bb_ + 2048); b3 = *(const i32x4*)(bb_ + 3072); } \
    asm volatile("s_barrier" ::: "memory"); \
  } while (0)

  STAGE_A8(0, 0); STAGE_B8(0, 0);
  STAGE_A8(0, 1); STAGE_B8(0, 1);
  STAGE_A8(1, 0); STAGE_B8(1, 0);
  asm volatile("s_waitcnt vmcnt(4)" ::: "memory");
  asm volatile("s_barrier" ::: "memory");
  {
    const char* ab_ = smem + aoff;
    afS[1][0] = *(const i32x4*)(ab_);
    afS[1][1] = *(const i32x4*)(ab_ + 1024);
    afS[1][2] = *(const i32x4*)(ab_ + 2048);
    afS[1][3] = *(const i32x4*)(ab_ + 3072);
    const char* bb_ = smem + 65536 + boff;
    b0 = *(const i32x4*)(bb_); b1 = *(const i32x4*)(bb_ + 1024);
    b2 = *(const i32x4*)(bb_ + 2048); b3 = *(const i32x4*)(bb_ + 3072);
  }

#pragma unroll 1
  for (int t = 0; t < NT; t += 2) {
    PH8(0, 0, 1, 0, 1, 0, 0, 0, 0, STAGE_A8(t + 1, 1), 1);
    PH8(0, 1, 0, 1, 0, 1, 1, 0, 1, STAGE_B8(t + 1, 1), 0);
    PH8(0, 1, 1, 0, 1, 0, 0, 0, 0, STAGE_A8(t + 2, 0), 1);
    PH8(1, 0, 0, 1, 0, 1, 1, 1, 0, STAGE_B8(t + 2, 0), 0);
    PH8(1, 0, 1, 0, 1, 0, 0, 0, 0, STAGE_A8(t + 2, 1), 1);
    PH8(1, 1, 0, 1, 0, 1, 1, 1, 1, STAGE_B8(t + 2, 1), 0);
    PH8(1, 1, 1, 0, 1, 0, 0, 0, 0, STAGE_A8(t + 3, 0), 1);
    PH8(0, 0, 0, 1, 0, 1, 1, 0, 0, STAGE_B8(t + 3, 0), 0);
  }

  const int r0 = bm + (wm << 7) + (kc << 2);
  const int c0 = bn + (wn << 6) + rl;
  float lsum = 0.f;
#pragma unroll
  for (int mi = 0; mi < 8; ++mi) {
#pragma unroll
    for (int nf = 0; nf < 4; ++nf) {
#pragma unroll
      for (int q = 0; q < 4; ++q) {
        const int r = r0 + (mi << 4) + q;
        const int c = c0 + (nf << 4);
        float v = (float)acc[mi][nf][q] * sA[r] * sB[c];
        v = fmaxf(v, 0.f);
        Cb[(size_t)r * N + c] = __float2bfloat16(v);
        if constexpr (EPI == 1) lsum += v;
      }
    }
  }
  if constexpr (EPI == 1) {
#pragma unroll
    for (int off = 32; off > 0; off >>= 1)
      lsum += __shfl_down(lsum, off);
    if (lane == 0) atomicAdd(vsum, lsum);
  }

#undef STAGE_A8
#undef STAGE_B8
#undef MFMA_ROW8
#undef PH8
}

// ============================================================================
// 128x128 2-barrier INT8 GEMM (verified) + XCD swizzle — pred:
// pred = (spq @ wuq^T) * sA[r] * sB[c] -> bf16 (no relu).
// ============================================================================
__global__ void __launch_bounds__(256)
gemm_i8_128(const uint8_t* __restrict__ A, const uint8_t* __restrict__ B,
            __hip_bfloat16* __restrict__ Cb, int M, int N, int K,
            const float* __restrict__ sA, const float* __restrict__ sB)
{
  __shared__ __align__(16) char smem[32768];
  const int tid  = threadIdx.x;
  const int lane = tid & 63;
  const int wave = tid >> 6;

  const int nwg = gridDim.x;
  const int bid = ((int)blockIdx.x % 8) * (nwg >> 3) + ((int)blockIdx.x >> 3);

  const int nbn = N >> 7;
  const int bm = (bid / nbn) << 7;
  const int bn = (bid % nbn) << 7;

  const int wm = (wave >> 1) << 6;
  const int wn = (wave & 1) << 6;

  i32x4 acc[4][4];
  const i32x4 izero = {0, 0, 0, 0};
#pragma unroll
  for (int i = 0; i < 4; ++i)
#pragma unroll
    for (int j = 0; j < 4; ++j)
      acc[i][j] = izero;

  const int srow = tid >> 3;
  const int schk = (tid & 7) ^ (srow & 7);
  const uint8_t* Ag = A + (size_t)(bm + srow) * K + (schk << 4);
  const uint8_t* Bg = B + (size_t)(bn + srow) * K + (schk << 4);
  char* ldsA = smem + (wave << 10);
  char* ldsB = smem + 16384 + (wave << 10);

  const int aoff0 = (wm + (lane & 15)) << 7;
  const int boff0 = 16384 + ((wn + (lane & 15)) << 7);
  const int kc = lane >> 4;
  const int sw = lane & 7;

  for (int k0 = 0; k0 < K; k0 += 128) {
#pragma unroll
    for (int i = 0; i < 4; ++i)
      load_lds16(Ag + (size_t)(i << 5) * K + k0, ldsA + (i << 12));
#pragma unroll
    for (int i = 0; i < 4; ++i)
      load_lds16(Bg + (size_t)(i << 5) * K + k0, ldsB + (i << 12));
    __syncthreads();
#pragma unroll
    for (int ks = 0; ks < 2; ++ks) {
      const int cb = ((kc + (ks << 2)) ^ sw) << 4;
      i32x4 af[4], bfr[4];
#pragma unroll
      for (int i = 0; i < 4; ++i)
        af[i] = *reinterpret_cast<const i32x4*>(smem + aoff0 + (i << 11) + cb);
#pragma unroll
      for (int j = 0; j < 4; ++j)
        bfr[j] = *reinterpret_cast<const i32x4*>(smem + boff0 + (j << 11) + cb);
#pragma unroll
      for (int i = 0; i < 4; ++i)
#pragma unroll
        for (int j = 0; j < 4; ++j)
          acc[i][j] = __builtin_amdgcn_mfma_i32_16x16x64_i8(af[i], bfr[j], acc[i][j], 0, 0, 0);
    }
    __syncthreads();
  }

  const int r0 = bm + wm + ((lane >> 4) << 2);
  const int c0 = bn + wn + (lane & 15);
#pragma unroll
  for (int i = 0; i < 4; ++i)
#pragma unroll
    for (int j = 0; j < 4; ++j)
#pragma unroll
      for (int q = 0; q < 4; ++q) {
        const int r = r0 + (i << 4) + q;
        const int c = c0 + (j << 4);
        Cb[(size_t)r * N + c] =
            __float2bfloat16((float)acc[i][j][q] * sA[r] * sB[c]);
      }
}

// ============================================================================
// 128x128 2-barrier INT8 gate GEMM + fused final epilogue:
// out = x + sigmoid(deq(xq@wgq^T) + bgate) * pred(bf16)   (f32 out)
// ============================================================================
__global__ void __launch_bounds__(256)
gemm_gate_i8(const uint8_t* __restrict__ A, const uint8_t* __restrict__ B,
             float* __restrict__ Cf, int M, int N, int K,
             const float* __restrict__ sA, const float* __restrict__ sB,
             const float* __restrict__ Xf, const __hip_bfloat16* __restrict__ PredBf,
             const float* __restrict__ Bgate)
{
  __shared__ __align__(16) char smem[32768];
  const int tid  = threadIdx.x;
  const int lane = tid & 63;
  const int wave = tid >> 6;

  const int nwg = gridDim.x;
  const int bid = ((int)blockIdx.x % 8) * (nwg >> 3) + ((int)blockIdx.x >> 3);

  const int nbn = N >> 7;
  const int bm = (bid / nbn) << 7;
  const int bn = (bid % nbn) << 7;

  const int wm = (wave >> 1) << 6;
  const int wn = (wave & 1) << 6;

  i32x4 acc[4][4];
  const i32x4 izero = {0, 0, 0, 0};
#pragma unroll
  for (int i = 0; i < 4; ++i)
#pragma unroll
    for (int j = 0; j < 4; ++j) acc[i][j] = izero;

  const int srow = tid >> 3;
  const int schk = (tid & 7) ^ (srow & 7);
  const uint8_t* Ag = A + (size_t)(bm + srow) * K + (schk << 4);
  const uint8_t* Bg = B + (size_t)(bn + srow) * K + (schk << 4);
  char* ldsA = smem + (wave << 10);
  char* ldsB = smem + 16384 + (wave << 10);

  const int aoff0 = (wm + (lane & 15)) << 7;
  const int boff0 = 16384 + ((wn + (lane & 15)) << 7);
  const int kc = lane >> 4;
  const int sw = lane & 7;

  for (int k0 = 0; k0 < K; k0 += 128) {
#pragma unroll
    for (int i = 0; i < 4; ++i)
      load_lds16(Ag + (size_t)(i << 5) * K + k0, ldsA + (i << 12));
#pragma unroll
    for (int i = 0; i < 4; ++i)
      load_lds16(Bg + (size_t)(i << 5) * K + k0, ldsB + (i << 12));
    __syncthreads();
#pragma unroll
    for (int ks = 0; ks < 2; ++ks) {
      const int cb = ((kc + (ks << 2)) ^ sw) << 4;
      i32x4 af[4], bfr[4];
#pragma unroll
      for (int i = 0; i < 4; ++i)
        af[i] = *reinterpret_cast<const i32x4*>(smem + aoff0 + (i << 11) + cb);
#pragma unroll
      for (int j = 0; j < 4; ++j)
        bfr[j] = *reinterpret_cast<const i32x4*>(smem + boff0 + (j << 11) + cb);
#pragma unroll
      for (int i = 0; i < 4; ++i)
#pragma unroll
        for (int j = 0; j < 4; ++j)
          acc[i][j] = __builtin_amdgcn_mfma_i32_16x16x64_i8(af[i], bfr[j], acc[i][j], 0, 0, 0);
    }
    __syncthreads();
  }

  const int r0 = bm + wm + ((lane >> 4) << 2);
  const int c0 = bn + wn + (lane & 15);
#pragma unroll
  for (int i = 0; i < 4; ++i)
#pragma unroll
    for (int j = 0; j < 4; ++j)
#pragma unroll
      for (int q = 0; q < 4; ++q) {
        const int r = r0 + (i << 4) + q;
        const int c = c0 + (j << 4);
        const size_t idx = (size_t)r * N + c;
        const float vg = (float)acc[i][j][q] * sA[r] * sB[c] + Bgate[c];
        const float g = 1.f / (1.f + __expf(-vg));
        Cf[idx] = Xf[idx] + g * __bfloat162float(PredBf[idx]);
      }
}

// ============================================================================
// kwta, wave-per-row (verified). Exact threshold via 16-step binary search on
// u16 bf16 keys (nonneg). Emits INT8 normalized row + scale.
// MODE 0: always write.  MODE 1: only when *vsumPtr >= EPS (else keep old).
// ============================================================================
template<int MODE>
__global__ void __launch_bounds__(256)
kwta_wave(const __hip_bfloat16* __restrict__ H, uint8_t* __restrict__ OUTQ,
          float* __restrict__ sA, const float* __restrict__ vsumPtr,
          const int* __restrict__ kptr)
{
  const int tid  = threadIdx.x;
  const int lane = tid & 63;
  const int w    = tid >> 6;
  const int row  = ((int)blockIdx.x << 2) + w;

  if constexpr (MODE == 1) {
    if (!(*vsumPtr >= 1e-10f)) return;
  }

  const uint4* h8 = (const uint4*)(H + (size_t)row * 4096);
  uint4 d[8];
#pragma unroll
  for (int i = 0; i < 8; ++i) d[i] = h8[(i << 6) + lane];

  const unsigned k = (unsigned)(*kptr);

  unsigned kmax = 0;
#pragma unroll
  for (int i = 0; i < 8; ++i) {
    const unsigned* p = (const unsigned*)&d[i];
#pragma unroll
    for (int c4 = 0; c4 < 4; ++c4) {
      kmax = max(kmax, p[c4] & 0xffffu);
      kmax = max(kmax, p[c4] >> 16);
    }
  }
#pragma unroll
  for (int off = 32; off > 0; off >>= 1) kmax = max(kmax, __shfl_xor(kmax, off));

  unsigned lo = 0, hi = 65536;
#pragma unroll 1
  for (int it = 0; it < 16; ++it) {
    const unsigned mid = (lo + hi) >> 1;
    unsigned c = 0;
#pragma unroll
    for (int i = 0; i < 8; ++i) {
      const unsigned* p = (const unsigned*)&d[i];
#pragma unroll
      for (int c4 = 0; c4 < 4; ++c4) {
        c += ((p[c4] & 0xffffu) >= mid) ? 1u : 0u;
        c += ((p[c4] >> 16) >= mid) ? 1u : 0u;
      }
    }
#pragma unroll
    for (int off = 32; off > 0; off >>= 1) c += __shfl_xor(c, off);
    if (c >= k) lo = mid; else hi = mid;
  }
  const unsigned threshKey = lo;

  float ss = 0.f;
#pragma unroll
  for (int i = 0; i < 8; ++i) {
    const unsigned* p = (const unsigned*)&d[i];
#pragma unroll
    for (int c4 = 0; c4 < 4; ++c4) {
#pragma unroll
      for (int hh = 0; hh < 2; ++hh) {
        const unsigned key = hh ? (p[c4] >> 16) : (p[c4] & 0xffffu);
        if (key >= threshKey) {
          const float v = __uint_as_float(key << 16);
          ss = fmaf(v, v, ss);
        }
      }
    }
  }
#pragma unroll
  for (int off = 32; off > 0; off >>= 1) ss += __shfl_xor(ss, off);
  const float inv = 1.f / fmaxf(sqrtf(ss), 1e-10f);

  const float vmaxf = __uint_as_float(kmax << 16);
  const float r127 = (kmax > 0) ? 127.f / vmaxf : 0.f;

  if (lane == 0) sA[row] = vmaxf * inv * (1.f / 127.f);

  uint2* o2 = (uint2*)(OUTQ + (size_t)row * 4096);
#pragma unroll
  for (int i = 0; i < 8; ++i) {
    const unsigned* p = (const unsigned*)&d[i];
    unsigned b[8];
#pragma unroll
    for (int c4 = 0; c4 < 4; ++c4) {
#pragma unroll
      for (int hh = 0; hh < 2; ++hh) {
        const unsigned key = hh ? (p[c4] >> 16) : (p[c4] & 0xffffu);
        unsigned q = 0;
        if (key >= threshKey && key > 0) {
          const float v = __uint_as_float(key << 16);
          q = (unsigned)__float2int_rn(v * r127) & 0xffu;
        }
        b[c4 * 2 + hh] = q;
      }
    }
    uint2 o;
    o.x = b[0] | (b[1] << 8) | (b[2] << 16) | (b[3] << 24);
    o.y = b[4] | (b[5] << 8) | (b[6] << 16) | (b[7] << 24);
    o2[(i << 6) + lane] = o;
  }
}

// ============================================================================
// Merged per-row quantization, one launch; also zero-inits vsum (block 0).
// ============================================================================
__global__ void __launch_bounds__(256)
quant_all(const float* __restrict__ X,  const float* __restrict__ Wd,
          const float* __restrict__ Wg, const float* __restrict__ Wc,
          const float* __restrict__ Wu,
          uint8_t* __restrict__ xq,  uint8_t* __restrict__ wdq,
          uint8_t* __restrict__ wgq, uint8_t* __restrict__ wcq,
          uint8_t* __restrict__ wuq,
          float* __restrict__ sx,  float* __restrict__ swd,
          float* __restrict__ swg, float* __restrict__ swc,
          float* __restrict__ swu, float* __restrict__ vsum)
{
  if (blockIdx.x == 0 && threadIdx.x == 0) *vsum = 0.f;

  const int wgl = ((int)blockIdx.x << 2) + (threadIdx.x >> 6);
  const int lane = threadIdx.x & 63;

  const float* W; uint8_t* q; float* s; int row; bool big;
  if      (wgl < 8192)  { W = X;  q = xq;  s = sx;  row = wgl;         big = false; }
  else if (wgl < 12288) { W = Wd; q = wdq; s = swd; row = wgl - 8192;  big = false; }
  else if (wgl < 13312) { W = Wg; q = wgq; s = swg; row = wgl - 12288; big = false; }
  else if (wgl < 17408) { W = Wc; q = wcq; s = swc; row = wgl - 13312; big = true; }
  else                  { W = Wu; q = wuq; s = swu; row = wgl - 17408; big = true; }

  if (!big) {
    const float4* src = (const float4*)(W + (size_t)row * 1024);
    float4 v[4];
    float am = 0.f;
#pragma unroll
    for (int i = 0; i < 4; ++i) {
      v[i] = src[(i << 6) + lane];
      am = fmaxf(am, fmaxf(fmaxf(fabsf(v[i].x), fabsf(v[i].y)),
                           fmaxf(fabsf(v[i].z), fabsf(v[i].w))));
    }
#pragma unroll
    for (int off = 32; off > 0; off >>= 1) am = fmaxf(am, __shfl_xor(am, off));
    const float rinv = (am > 0.f) ? 127.f / am : 0.f;
    uint4 o;
    unsigned* ob = (unsigned*)&o;
#pragma unroll
    for (int i = 0; i < 4; ++i) {
      const unsigned b0 = (unsigned)__float2int_rn(v[i].x * rinv) & 0xffu;
      const unsigned b1 = (unsigned)__float2int_rn(v[i].y * rinv) & 0xffu;
      const unsigned b2 = (unsigned)__float2int_rn(v[i].z * rinv) & 0xffu;
      const unsigned b3 = (unsigned)__float2int_rn(v[i].w * rinv) & 0xffu;
      ob[i] = b0 | (b1 << 8) | (b2 << 16) | (b3 << 24);
    }
    ((uint4*)(q + (size_t)row * 1024))[lane] = o;
    if (lane == 0) s[row] = am * (1.f / 127.f);
  } else {
    const float4* src = (const float4*)(W + (size_t)row * 4096);
    float4 v[16];
    float am = 0.f;
#pragma unroll
    for (int i = 0; i < 16; ++i) {
      v[i] = src[(i << 6) + lane];
      am = fmaxf(am, fmaxf(fmaxf(fabsf(v[i].x), fabsf(v[i].y)),
                           fmaxf(fabsf(v[i].z), fabsf(v[i].w))));
    }
#pragma unroll
    for (int off = 32; off > 0; off >>= 1) am = fmaxf(am, __shfl_xor(am, off));
    const float rinv = (am > 0.f) ? 127.f / am : 0.f;
    unsigned* qo = (unsigned*)(q + (size_t)row * 4096);
#pragma unroll
    for (int i = 0; i < 16; ++i) {
      const unsigned b0 = (unsigned)__float2int_rn(v[i].x * rinv) & 0xffu;
      const unsigned b1 = (unsigned)__float2int_rn(v[i].y * rinv) & 0xffu;
      const unsigned b2 = (unsigned)__float2int_rn(v[i].z * rinv) & 0xffu;
      const unsigned b3 = (unsigned)__float2int_rn(v[i].w * rinv) & 0xffu;
      qo[(i << 6) + lane] = b0 | (b1 << 8) | (b2 << 16) | (b3 << 24);
    }
    if (lane == 0) s[row] = am * (1.f / 127.f);
  }
}

__global__ void diag_kernel(float* out, float mb)
{
  if (threadIdx.x == 0 && blockIdx.x == 0) out[0] = -mb;
}

extern "C" void kernel_launch(void* const* d_in, const int* in_sizes, int n_in,
                              void* d_out, int out_size, void* d_ws, size_t ws_size,
                              hipStream_t stream)
{
  const float* x     = (const float*)d_in[0]; // (8192,1024)
  const float* Wdown = (const float*)d_in[1]; // (4096,1024)
  const float* Wup   = (const float*)d_in[2]; // (1024,4096)
  const float* Wgate = (const float*)d_in[3]; // (1024,1024)
  const float* bgate = (const float*)d_in[4]; // (1024,)
  const float* Wca3  = (const float*)d_in[5]; // (4096,4096)
  const int*   kptr  = (const int*)d_in[6];

  const size_t OFF_XQ   = 0;         //  8 MB i8 x
  const size_t OFF_WDQ  = 8388608;   //  4 MB i8 W_down
  const size_t OFF_WGQ  = 12582912;  //  1 MB i8 W_gate
  const size_t OFF_WCQ  = 13631488;  // 16 MB i8 W_ca3
  const size_t OFF_WUQ  = 30408704;  //  4 MB i8 W_up
  const size_t OFF_SX   = 34603008;  // 32 KB
  const size_t OFF_SWD  = 34635776;  // 16 KB
  const size_t OFF_SWG  = 34652160;  //  4 KB
  const size_t OFF_SWC  = 34656256;  // 16 KB
  const size_t OFF_SWU  = 34672640;  //  4 KB
  const size_t OFF_SA   = 34676736;  // 32 KB
  const size_t OFF_VSUM = 34709504;  //  4 KB pad
  const size_t OFF_SPQ  = 34713600;  // 32 MB i8 sparse/successor
  const size_t OFF_H    = 68268032;  // 64 MB bf16 h1/h2; pred (16 MB bf16) aliases
  const size_t NEED     = 135376896;

  if (ws_size < NEED) {
    diag_kernel<<<1, 64, 0, stream>>>((float*)d_out, (float)(ws_size >> 20));
    return;
  }

  char* ws = (char*)d_ws;
  uint8_t*        xq   = (uint8_t*)       (ws + OFF_XQ);
  uint8_t*        wdq  = (uint8_t*)       (ws + OFF_WDQ);
  uint8_t*        wgq  = (uint8_t*)       (ws + OFF_WGQ);
  uint8_t*        wcq  = (uint8_t*)       (ws + OFF_WCQ);
  uint8_t*        wuq  = (uint8_t*)       (ws + OFF_WUQ);
  float*          sx   = (float*)         (ws + OFF_SX);
  float*          swd  = (float*)         (ws + OFF_SWD);
  float*          swg  = (float*)         (ws + OFF_SWG);
  float*          swc  = (float*)         (ws + OFF_SWC);
  float*          swu  = (float*)         (ws + OFF_SWU);
  float*          sA   = (float*)         (ws + OFF_SA);
  float*          vsum = (float*)         (ws + OFF_VSUM);
  uint8_t*        spq  = (uint8_t*)       (ws + OFF_SPQ);
  __hip_bfloat16* h    = (__hip_bfloat16*)(ws + OFF_H);
  __hip_bfloat16* pred = (__hip_bfloat16*)(ws + OFF_H);   // aliases h (dead by then)

  // quantize all inputs/weights to i8 with per-row scales; zero vsum
  quant_all<<<4608, 256, 0, stream>>>(x, Wdown, Wgate, Wca3, Wup,
                                      xq, wdq, wgq, wcq, wuq,
                                      sx, swd, swg, swc, swu, vsum);

  // h1 = relu(sx*swd * (xq @ wdq^T)) -> bf16   [i8 8-phase 256^2, supertile]
  gemm_i8_8ph<0><<<(MROWS >> 8) * (DN >> 8), 512, 131072, stream>>>(
      xq, wdq, h, MROWS, DN, DD, nullptr, sx, swd);
  // sparse = kwta(h1)/norm -> i8 + scale
  kwta_wave<0><<<MROWS / 4, 256, 0, stream>>>(h, spq, sA, nullptr, kptr);
  // h2 = relu(sA*swc * (spq @ wcq^T)) -> bf16, sum -> vsum   [i8 8-phase]
  gemm_i8_8ph<1><<<(MROWS >> 8) * (DN >> 8), 512, 131072, stream>>>(
      spq, wcq, h, MROWS, DN, DN, vsum, sA, swc);
  // successor = valid ? kwta(h2)/norm : sparse (i8 + scale, in-place)
  kwta_wave<1><<<MROWS / 4, 256, 0, stream>>>(h, spq, sA, vsum, kptr);
  // pred = (spq @ wuq^T) deq -> bf16   [i8 128^2 + swizzle, grid 512]
  gemm_i8_128<<<(MROWS >> 7) * (DD >> 7), 256, 0, stream>>>(
      spq, wuq, pred, MROWS, DD, DN, sA, swu);
  // out = x + sigmoid(deq(xq @ wgq^T) + bgate) * pred   [i8 128^2]
  gemm_gate_i8<<<(MROWS >> 7) * (DD >> 7), 256, 0, stream>>>(
      xq, wgq, (float*)d_out, MROWS, DD, DD, sx, swg, x, pred, bgate);
}